// Round 1
// baseline (1013.598 us; speedup 1.0000x reference)
//
#include <hip/hip_runtime.h>

#define N_NODES 100000
#define E_EDGES 1600000
#define EP_EDGES (E_EDGES + N_NODES)   // 1,700,000 with self loops
#define HID 64
#define SLOPE 0.2f
#define BN_EPS 1e-5f

// ---------- helpers ----------
__device__ __forceinline__ float bflo(unsigned int u) { return __uint_as_float(u << 16); }
__device__ __forceinline__ float bfhi(unsigned int u) { return __uint_as_float(u & 0xffff0000u); }
__device__ __forceinline__ unsigned short f2bf(float f) {
    unsigned int u = __float_as_uint(f);
    unsigned int r = (u + 0x7fffu + ((u >> 16) & 1u)) >> 16;
    return (unsigned short)r;
}

// ---------- CSR build ----------
__global__ void deg_count(const int* __restrict__ dst, int* __restrict__ deg) {
    int i = blockIdx.x * 256 + threadIdx.x;
    if (i < E_EDGES)      atomicAdd(&deg[dst[i]], 1);
    else if (i < EP_EDGES) atomicAdd(&deg[i - E_EDGES], 1);   // self loop
}

__global__ void scan_a(const int* __restrict__ deg, int* __restrict__ row_ptr, int* __restrict__ bsum) {
    __shared__ int tmp[1024];
    int tid = threadIdx.x;
    int i = blockIdx.x * 1024 + tid;
    int v = (i < N_NODES) ? deg[i] : 0;
    tmp[tid] = v; __syncthreads();
    for (int ofs = 1; ofs < 1024; ofs <<= 1) {
        int t2 = (tid >= ofs) ? tmp[tid - ofs] : 0;
        __syncthreads();
        tmp[tid] += t2;
        __syncthreads();
    }
    if (i < N_NODES) row_ptr[i + 1] = tmp[tid];
    if (tid == 1023) bsum[blockIdx.x] = tmp[1023];
}

__global__ void scan_b(int* __restrict__ bsum, int nb) {
    if (threadIdx.x == 0 && blockIdx.x == 0) {
        int run = 0;
        for (int b = 0; b < nb; ++b) { int t = bsum[b]; bsum[b] = run; run += t; }
    }
}

__global__ void scan_c(int* __restrict__ cursor, int* __restrict__ row_ptr, const int* __restrict__ bsum) {
    int i = blockIdx.x * 256 + threadIdx.x;
    if (i < N_NODES) {
        int d = cursor[i];
        int incl = row_ptr[i + 1] + bsum[i >> 10];
        row_ptr[i + 1] = incl;
        cursor[i] = incl - d;           // exclusive start
        if (i == 0) row_ptr[0] = 0;
    }
}

__global__ void scatter_edges(const int* __restrict__ src, const int* __restrict__ dst,
                              int* __restrict__ cursor, int* __restrict__ col) {
    int i = blockIdx.x * 256 + threadIdx.x;
    if (i < E_EDGES) {
        int pos = atomicAdd(&cursor[dst[i]], 1);
        col[pos] = src[i];
    } else if (i < EP_EDGES) {
        int v = i - E_EDGES;
        int pos = atomicAdd(&cursor[v], 1);
        col[pos] = v;
    }
}

// ---------- encoder: h = x @ W_enc + b_enc  [N,64] ----------
__global__ __launch_bounds__(256) void encoder(const float* __restrict__ x, const float* __restrict__ W,
                                               const float* __restrict__ b, float* __restrict__ h) {
    int t = threadIdx.x;
    int j = t & 63, q = t >> 6;
    float wcol[64];
#pragma unroll
    for (int k = 0; k < 64; ++k) wcol[k] = W[k * 64 + j];
    float bj = b[j];
    __shared__ float sx[32][64];
    for (int base = blockIdx.x * 32; base < N_NODES; base += gridDim.x * 32) {
        __syncthreads();
        for (int i = t; i < 2048; i += 256) {
            int node = base + (i >> 6);
            sx[i >> 6][i & 63] = (node < N_NODES) ? x[(size_t)node * 64 + (i & 63)] : 0.f;
        }
        __syncthreads();
        for (int r = q; r < 32; r += 4) {
            int node = base + r;
            if (node >= N_NODES) continue;
            float acc = bj;
            const float4* s4 = (const float4*)sx[r];
#pragma unroll
            for (int k4 = 0; k4 < 16; ++k4) {
                float4 v = s4[k4];
                acc += v.x * wcol[4 * k4] + v.y * wcol[4 * k4 + 1] + v.z * wcol[4 * k4 + 2] + v.w * wcol[4 * k4 + 3];
            }
            h[(size_t)node * 64 + j] = acc;
        }
    }
}

// ---------- per-layer transforms: xl = act(h) @ Wl + bl, xr likewise, packed bf16 ----------
// output layout: ushort at [v*128 + 2*c + head]  (so u32 at [v*64+c] = (head1<<16)|head0)
template <int BN>
__global__ __launch_bounds__(256) void layer_gemm(const float* __restrict__ hin,
                                                  const float* __restrict__ Wl, const float* __restrict__ bl,
                                                  const float* __restrict__ Wr, const float* __restrict__ br,
                                                  const float* __restrict__ scale, const float* __restrict__ shift,
                                                  unsigned short* __restrict__ xl, unsigned short* __restrict__ xr) {
    int t = threadIdx.x;
    int tt = t & 127;
    bool isR = t >= 128;
    int c = tt >> 1, head = tt & 1;
    int colW = head * 64 + c;
    const float* W = isR ? Wr : Wl;
    float wcol[64];
#pragma unroll
    for (int k = 0; k < 64; ++k) wcol[k] = W[k * 128 + colW];
    float bj = (isR ? br : bl)[colW];
    unsigned short* dstp = isR ? xr : xl;
    __shared__ float sh[8][64];
    for (int base = blockIdx.x * 8; base < N_NODES; base += gridDim.x * 8) {
        __syncthreads();
        for (int i = t; i < 512; i += 256) {
            int node = base + (i >> 6);
            float v = (node < N_NODES) ? hin[(size_t)node * 64 + (i & 63)] : 0.f;
            if (BN) v = fmaxf(v * scale[i & 63] + shift[i & 63], 0.f);
            sh[i >> 6][i & 63] = v;
        }
        __syncthreads();
        int lim = min(8, N_NODES - base);
        for (int r = 0; r < lim; ++r) {
            float acc = bj;
            const float4* s4 = (const float4*)sh[r];
#pragma unroll
            for (int k4 = 0; k4 < 16; ++k4) {
                float4 v = s4[k4];
                acc += v.x * wcol[4 * k4] + v.y * wcol[4 * k4 + 1] + v.z * wcol[4 * k4 + 2] + v.w * wcol[4 * k4 + 3];
            }
            dstp[(size_t)(base + r) * 128 + tt] = f2bf(acc);
        }
    }
}

// ---------- fused GATv2 edge phase: online softmax aggregation, one wave per dst ----------
__global__ __launch_bounds__(256) void aggregate(const unsigned int* __restrict__ xl,
                                                 const unsigned int* __restrict__ xr,
                                                 const int* __restrict__ row_ptr, const int* __restrict__ col,
                                                 const float* __restrict__ att_l, const float* __restrict__ bias_l,
                                                 float* __restrict__ hn, float* __restrict__ bnsum) {
    int lane = threadIdx.x & 63, wid = threadIdx.x >> 6;
    float at0 = att_l[lane], at1 = att_l[64 + lane];
    float bi = bias_l[lane];
    float psum = 0.f, psq = 0.f;
    int w = blockIdx.x * 4 + wid, nw = gridDim.x * 4;
    for (int v = w; v < N_NODES; v += nw) {
        unsigned int rp = xr[(size_t)v * 64 + lane];
        float r0 = bflo(rp), r1 = bfhi(rp);
        int beg = row_ptr[v], end = row_ptr[v + 1];
        float m0 = -3e38f, m1 = -3e38f, s0 = 0.f, s1 = 0.f, a0 = 0.f, a1 = 0.f;
        unsigned int lp = xl[(size_t)col[beg] * 64 + lane];
        for (int i = beg; i < end; ++i) {
            unsigned int lpn = 0;
            if (i + 1 < end) lpn = xl[(size_t)col[i + 1] * 64 + lane];   // prefetch
            float l0 = bflo(lp), l1 = bfhi(lp);
            float z0 = l0 + r0; z0 = z0 > 0.f ? z0 : SLOPE * z0;
            float z1 = l1 + r1; z1 = z1 > 0.f ? z1 : SLOPE * z1;
            float t0 = z0 * at0, t1 = z1 * at1;
#pragma unroll
            for (int o = 32; o; o >>= 1) { t0 += __shfl_xor(t0, o, 64); t1 += __shfl_xor(t1, o, 64); }
            float nm0 = fmaxf(m0, t0), nm1 = fmaxf(m1, t1);
            float c0 = __expf(m0 - nm0), c1 = __expf(m1 - nm1);
            float p0 = __expf(t0 - nm0), p1 = __expf(t1 - nm1);
            s0 = s0 * c0 + p0; s1 = s1 * c1 + p1;
            a0 = a0 * c0 + p0 * l0; a1 = a1 * c1 + p1 * l1;
            m0 = nm0; m1 = nm1;
            lp = lpn;
        }
        float hv = 0.5f * (a0 / s0 + a1 / s1) + bi;
        hn[(size_t)v * 64 + lane] = hv;
        psum += hv; psq += hv * hv;
    }
    __shared__ float sr[2][4][64];
    sr[0][wid][lane] = psum; sr[1][wid][lane] = psq;
    __syncthreads();
    if (wid == 0)
        atomicAdd(&bnsum[lane], sr[0][0][lane] + sr[0][1][lane] + sr[0][2][lane] + sr[0][3][lane]);
    else if (wid == 1)
        atomicAdd(&bnsum[64 + lane], sr[1][0][lane] + sr[1][1][lane] + sr[1][2][lane] + sr[1][3][lane]);
}

// ---------- BN param finalize ----------
__global__ void bn_final(const float* __restrict__ bnsum, const float* __restrict__ gamma,
                         const float* __restrict__ beta, float* __restrict__ scale, float* __restrict__ shift) {
    int c = threadIdx.x;
    if (c < 64) {
        float mu = bnsum[c] * (1.f / N_NODES);
        float ex2 = bnsum[64 + c] * (1.f / N_NODES);
        float var = ex2 - mu * mu;
        float sc = gamma[c] * rsqrtf(var + BN_EPS);
        scale[c] = sc;
        shift[c] = beta[c] - mu * sc;
    }
}

// ---------- pool (batch sorted): BN+ReLU on the fly, run-length local accumulation ----------
__global__ __launch_bounds__(256) void pool(const float* __restrict__ hn, const int* __restrict__ batch,
                                            const float* __restrict__ scale, const float* __restrict__ shift,
                                            float* __restrict__ gpool, float* __restrict__ gcnt) {
    int t = threadIdx.x;
    int c = t & 63, r = t >> 6;
    int base = blockIdx.x * 64;
    float acc = 0.f, cnt = 0.f;
    int curg = -1;
    for (int j = 0; j < 16; ++j) {
        int node = base + r * 16 + j;
        if (node >= N_NODES) break;
        int g = batch[node];
        float val = fmaxf(hn[(size_t)node * 64 + c] * scale[c] + shift[c], 0.f);
        if (g != curg) {
            if (curg >= 0) {
                atomicAdd(&gpool[curg * 64 + c], acc);
                if (c == 0) atomicAdd(&gcnt[curg], cnt);
            }
            curg = g; acc = 0.f; cnt = 0.f;
        }
        acc += val; cnt += 1.f;
    }
    if (curg >= 0) {
        atomicAdd(&gpool[curg * 64 + c], acc);
        if (c == 0) atomicAdd(&gcnt[curg], cnt);
    }
}

// ---------- classifier ----------
__global__ void classify(const float* __restrict__ gpool, const float* __restrict__ gcnt,
                         const float* __restrict__ Wc, const float* __restrict__ bc, float* __restrict__ out) {
    int t = threadIdx.x;
    if (t >= 640) return;
    int b = t / 10, o = t % 10;
    float inv = 1.f / fmaxf(gcnt[b], 1.f);
    float acc = 0.f;
    for (int c = 0; c < 64; ++c) acc += gpool[b * 64 + c] * Wc[c * 10 + o];
    out[t] = acc * inv + bc[o];
}

extern "C" void kernel_launch(void* const* d_in, const int* in_sizes, int n_in,
                              void* d_out, int out_size, void* d_ws, size_t ws_size,
                              hipStream_t stream) {
    (void)in_sizes; (void)n_in; (void)out_size; (void)ws_size;
    const float* x     = (const float*)d_in[0];
    const int*   ei    = (const int*)d_in[1];
    const int*   batch = (const int*)d_in[2];
    const float* W_enc = (const float*)d_in[3];
    const float* b_enc = (const float*)d_in[4];
    const float* Wl    = (const float*)d_in[5];
    const float* bl    = (const float*)d_in[6];
    const float* Wr    = (const float*)d_in[7];
    const float* br    = (const float*)d_in[8];
    const float* att   = (const float*)d_in[9];
    const float* bias  = (const float*)d_in[10];
    const float* gamma = (const float*)d_in[11];
    const float* beta  = (const float*)d_in[12];
    const float* Wc    = (const float*)d_in[13];
    const float* bc    = (const float*)d_in[14];
    float* out = (float*)d_out;

    char* ws = (char*)d_ws;
    size_t off = 0;
    auto A = [&](size_t bytes) { size_t r = off; off += (bytes + 255) & ~(size_t)255; return r; };
    int* row_ptr = (int*)(ws + A((N_NODES + 1) * 4));
    int* cursor  = (int*)(ws + A((size_t)N_NODES * 4));
    int* colv    = (int*)(ws + A((size_t)EP_EDGES * 4));
    int* bsum    = (int*)(ws + A(512));
    float* h     = (float*)(ws + A((size_t)N_NODES * 64 * 4));
    float* hn    = (float*)(ws + A((size_t)N_NODES * 64 * 4));
    unsigned short* xl = (unsigned short*)(ws + A((size_t)N_NODES * 128 * 2));
    unsigned short* xr = (unsigned short*)(ws + A((size_t)N_NODES * 128 * 2));
    float* bns     = (float*)(ws + A(2 * 128 * 4));
    float* bnscale = (float*)(ws + A(2 * 64 * 4));
    float* bnshift = (float*)(ws + A(2 * 64 * 4));
    float* gpool   = (float*)(ws + A(64 * 64 * 4));
    float* gcnt    = (float*)(ws + A(64 * 4));

    const int* srcv = ei;
    const int* dstv = ei + E_EDGES;

    hipMemsetAsync(cursor, 0, (size_t)N_NODES * 4, stream);
    hipMemsetAsync(bns, 0, 2 * 128 * 4, stream);
    hipMemsetAsync(gpool, 0, 64 * 64 * 4, stream);
    hipMemsetAsync(gcnt, 0, 64 * 4, stream);

    deg_count<<<(EP_EDGES + 255) / 256, 256, 0, stream>>>(dstv, cursor);
    scan_a<<<98, 1024, 0, stream>>>(cursor, row_ptr, bsum);
    scan_b<<<1, 64, 0, stream>>>(bsum, 98);
    scan_c<<<(N_NODES + 255) / 256, 256, 0, stream>>>(cursor, row_ptr, bsum);
    scatter_edges<<<(EP_EDGES + 255) / 256, 256, 0, stream>>>(srcv, dstv, cursor, colv);

    encoder<<<512, 256, 0, stream>>>(x, W_enc, b_enc, h);

    // layer 0
    layer_gemm<0><<<1024, 256, 0, stream>>>(h, Wl, bl, Wr, br, nullptr, nullptr, xl, xr);
    aggregate<<<2048, 256, 0, stream>>>((const unsigned int*)xl, (const unsigned int*)xr,
                                        row_ptr, colv, att, bias, hn, bns);
    bn_final<<<1, 64, 0, stream>>>(bns, gamma, beta, bnscale, bnshift);

    // layer 1
    layer_gemm<1><<<1024, 256, 0, stream>>>(hn, Wl + 64 * 128, bl + 128, Wr + 64 * 128, br + 128,
                                            bnscale, bnshift, xl, xr);
    aggregate<<<2048, 256, 0, stream>>>((const unsigned int*)xl, (const unsigned int*)xr,
                                        row_ptr, colv, att + 128, bias + 64, h, bns + 128);
    bn_final<<<1, 64, 0, stream>>>(bns + 128, gamma + 64, beta + 64, bnscale + 64, bnshift + 64);

    pool<<<(N_NODES + 63) / 64, 256, 0, stream>>>(h, batch, bnscale + 64, bnshift + 64, gpool, gcnt);
    classify<<<1, 640, 0, stream>>>(gpool, gcnt, Wc, bc, out);
}

// Round 2
// 730.096 us; speedup vs baseline: 1.3883x; 1.3883x over previous
//
#include <hip/hip_runtime.h>

#define N_NODES 100000
#define E_EDGES 1600000
#define EP_EDGES (E_EDGES + N_NODES)   // 1,700,000 with self loops
#define HID 64
#define SLOPE 0.2f
#define BN_EPS 1e-5f

// ---------- helpers ----------
__device__ __forceinline__ float bflo(unsigned int u) { return __uint_as_float(u << 16); }
__device__ __forceinline__ float bfhi(unsigned int u) { return __uint_as_float(u & 0xffff0000u); }
__device__ __forceinline__ unsigned short f2bf(float f) {
    unsigned int u = __float_as_uint(f);
    unsigned int r = (u + 0x7fffu + ((u >> 16) & 1u)) >> 16;
    return (unsigned short)r;
}

// ---------- CSR build ----------
__global__ void deg_count(const int* __restrict__ dst, int* __restrict__ deg) {
    int i = blockIdx.x * 256 + threadIdx.x;
    if (i < E_EDGES)      atomicAdd(&deg[dst[i]], 1);
    else if (i < EP_EDGES) atomicAdd(&deg[i - E_EDGES], 1);   // self loop
}

__global__ void scan_a(const int* __restrict__ deg, int* __restrict__ row_ptr, int* __restrict__ bsum) {
    __shared__ int tmp[1024];
    int tid = threadIdx.x;
    int i = blockIdx.x * 1024 + tid;
    int v = (i < N_NODES) ? deg[i] : 0;
    tmp[tid] = v; __syncthreads();
    for (int ofs = 1; ofs < 1024; ofs <<= 1) {
        int t2 = (tid >= ofs) ? tmp[tid - ofs] : 0;
        __syncthreads();
        tmp[tid] += t2;
        __syncthreads();
    }
    if (i < N_NODES) row_ptr[i + 1] = tmp[tid];
    if (tid == 1023) bsum[blockIdx.x] = tmp[1023];
}

__global__ void scan_b(int* __restrict__ bsum, int nb) {
    if (threadIdx.x == 0 && blockIdx.x == 0) {
        int run = 0;
        for (int b = 0; b < nb; ++b) { int t = bsum[b]; bsum[b] = run; run += t; }
    }
}

__global__ void scan_c(int* __restrict__ cursor, int* __restrict__ row_ptr, const int* __restrict__ bsum) {
    int i = blockIdx.x * 256 + threadIdx.x;
    if (i < N_NODES) {
        int d = cursor[i];
        int incl = row_ptr[i + 1] + bsum[i >> 10];
        row_ptr[i + 1] = incl;
        cursor[i] = incl - d;           // exclusive start
        if (i == 0) row_ptr[0] = 0;
    }
}

__global__ void scatter_edges(const int* __restrict__ src, const int* __restrict__ dst,
                              int* __restrict__ cursor, int* __restrict__ col) {
    int i = blockIdx.x * 256 + threadIdx.x;
    if (i < E_EDGES) {
        int pos = atomicAdd(&cursor[dst[i]], 1);
        col[pos] = src[i];
    } else if (i < EP_EDGES) {
        int v = i - E_EDGES;
        int pos = atomicAdd(&cursor[v], 1);
        col[pos] = v;
    }
}

// ---------- fold encoder into layer-0 weights: Wc = W_enc @ W, bc = b_enc @ W + b ----------
__global__ __launch_bounds__(256) void fuse_enc(const float* __restrict__ We, const float* __restrict__ be,
                                                const float* __restrict__ Wl, const float* __restrict__ bl,
                                                const float* __restrict__ Wr, const float* __restrict__ br,
                                                float* __restrict__ Wcl, float* __restrict__ bcl,
                                                float* __restrict__ Wcr, float* __restrict__ bcr) {
    __shared__ float sWe[64][64];   // sWe[m][k] = We[k][m]
    __shared__ float sbe[64];
    int t = threadIdx.x;
    for (int i = t; i < 4096; i += 256) sWe[i & 63][i >> 6] = We[i];
    if (t < 64) sbe[t] = be[t];
    __syncthreads();
    int j = t & 127, side = t >> 7;
    const float* W  = side ? Wr : Wl;
    const float* bb = side ? br : bl;
    float acc[64];
#pragma unroll
    for (int k = 0; k < 64; ++k) acc[k] = 0.f;
    float bacc = bb[j];
    for (int m = 0; m < 64; ++m) {
        float wv = W[m * 128 + j];
        bacc += sbe[m] * wv;
#pragma unroll
        for (int k = 0; k < 64; ++k) acc[k] += sWe[m][k] * wv;
    }
    float* Wc = side ? Wcr : Wcl;
#pragma unroll
    for (int k = 0; k < 64; ++k) Wc[k * 128 + j] = acc[k];
    (side ? bcr : bcl)[j] = bacc;
}

// ---------- per-layer transforms: xl = act(h) @ Wl + bl, xr likewise, packed bf16 ----------
// output layout: ushort at [v*128 + 2*c + head]  (so u32 at [v*64+c] = (head1<<16)|head0)
template <int BN>
__global__ __launch_bounds__(256) void layer_gemm(const float* __restrict__ hin,
                                                  const float* __restrict__ Wl, const float* __restrict__ bl,
                                                  const float* __restrict__ Wr, const float* __restrict__ br,
                                                  const float* __restrict__ scale, const float* __restrict__ shift,
                                                  unsigned short* __restrict__ xl, unsigned short* __restrict__ xr) {
    int t = threadIdx.x;
    int tt = t & 127;
    bool isR = t >= 128;
    int c = tt >> 1, head = tt & 1;
    int colW = head * 64 + c;
    const float* W = isR ? Wr : Wl;
    float wcol[64];
#pragma unroll
    for (int k = 0; k < 64; ++k) wcol[k] = W[k * 128 + colW];
    float bj = (isR ? br : bl)[colW];
    unsigned short* dstp = isR ? xr : xl;
    __shared__ float sh[8][64];
    for (int base = blockIdx.x * 8; base < N_NODES; base += gridDim.x * 8) {
        __syncthreads();
        for (int i = t; i < 512; i += 256) {
            int node = base + (i >> 6);
            float v = (node < N_NODES) ? hin[(size_t)node * 64 + (i & 63)] : 0.f;
            if (BN) v = fmaxf(v * scale[i & 63] + shift[i & 63], 0.f);
            sh[i >> 6][i & 63] = v;
        }
        __syncthreads();
        int lim = min(8, N_NODES - base);
        for (int r = 0; r < lim; ++r) {
            float acc = bj;
            const float4* s4 = (const float4*)sh[r];
#pragma unroll
            for (int k4 = 0; k4 < 16; ++k4) {
                float4 v = s4[k4];
                acc += v.x * wcol[4 * k4] + v.y * wcol[4 * k4 + 1] + v.z * wcol[4 * k4 + 2] + v.w * wcol[4 * k4 + 3];
            }
            dstp[(size_t)(base + r) * 128 + tt] = f2bf(acc);
        }
    }
}

// ---------- fused GATv2 edge phase: 4 edges per wave iteration (16-lane groups), direct exp ----------
__global__ __launch_bounds__(256) void aggregate(const uint4* __restrict__ xl4,
                                                 const uint4* __restrict__ xr4,
                                                 const int* __restrict__ row_ptr, const int* __restrict__ col,
                                                 const float* __restrict__ att_l, const float* __restrict__ bias_l,
                                                 float* __restrict__ hn, float* __restrict__ bnsum) {
    int lane = threadIdx.x & 63, wid = threadIdx.x >> 6;
    int q = lane >> 4, k = lane & 15;
    float4 at0 = *(const float4*)(att_l + 4 * k);        // head0 att, channels 4k..4k+3
    float4 at1 = *(const float4*)(att_l + 64 + 4 * k);   // head1
    float4 bi  = *(const float4*)(bias_l + 4 * k);
    float ps[4] = {0.f, 0.f, 0.f, 0.f}, pq[4] = {0.f, 0.f, 0.f, 0.f};
    int w = blockIdx.x * 4 + wid, nw = gridDim.x * 4;
    for (int v = w; v < N_NODES; v += nw) {
        uint4 rp = xr4[(size_t)v * 16 + k];
        float r0[4] = {bflo(rp.x), bflo(rp.y), bflo(rp.z), bflo(rp.w)};
        float r1[4] = {bfhi(rp.x), bfhi(rp.y), bfhi(rp.z), bfhi(rp.w)};
        int beg = row_ptr[v], end = row_ptr[v + 1];
        float s0 = 0.f, s1 = 0.f;
        float a0[4] = {0.f, 0.f, 0.f, 0.f}, a1[4] = {0.f, 0.f, 0.f, 0.f};
        bool vf = (beg + q) < end;
        int c0 = col[vf ? beg + q : beg];
        uint4 lp = xl4[(size_t)c0 * 16 + k];
        for (int i = beg; i < end; i += 4) {
            uint4 lpn = lp;
            int in = i + 4;
            if (in < end) {                               // wave-uniform branch: prefetch next 4 edges
                bool vn = (in + q) < end;
                int cn = col[vn ? in + q : beg];
                lpn = xl4[(size_t)cn * 16 + k];
            }
            float l0[4] = {bflo(lp.x), bflo(lp.y), bflo(lp.z), bflo(lp.w)};
            float l1[4] = {bfhi(lp.x), bfhi(lp.y), bfhi(lp.z), bfhi(lp.w)};
            float at0a[4] = {at0.x, at0.y, at0.z, at0.w};
            float at1a[4] = {at1.x, at1.y, at1.z, at1.w};
            float t0 = 0.f, t1 = 0.f;
#pragma unroll
            for (int j = 0; j < 4; ++j) {
                float z0 = l0[j] + r0[j]; z0 = z0 > 0.f ? z0 : SLOPE * z0;
                float z1 = l1[j] + r1[j]; z1 = z1 > 0.f ? z1 : SLOPE * z1;
                t0 = fmaf(z0, at0a[j], t0);
                t1 = fmaf(z1, at1a[j], t1);
            }
#pragma unroll
            for (int o = 1; o <= 8; o <<= 1) {            // reduce within 16-lane group
                t0 += __shfl_xor(t0, o, 64);
                t1 += __shfl_xor(t1, o, 64);
            }
            bool valid = (i + q) < end;
            float p0 = valid ? __expf(t0) : 0.f;          // logits tiny: no max-subtraction needed
            float p1 = valid ? __expf(t1) : 0.f;
            s0 += p0; s1 += p1;
#pragma unroll
            for (int j = 0; j < 4; ++j) {
                a0[j] = fmaf(p0, l0[j], a0[j]);
                a1[j] = fmaf(p1, l1[j], a1[j]);
            }
            lp = lpn;
        }
        // combine the 4 groups
#pragma unroll
        for (int o = 16; o <= 32; o <<= 1) {
            s0 += __shfl_xor(s0, o, 64); s1 += __shfl_xor(s1, o, 64);
#pragma unroll
            for (int j = 0; j < 4; ++j) {
                a0[j] += __shfl_xor(a0[j], o, 64);
                a1[j] += __shfl_xor(a1[j], o, 64);
            }
        }
        float inv0 = 1.0f / s0, inv1 = 1.0f / s1;
        float bia[4] = {bi.x, bi.y, bi.z, bi.w};
        float hv[4];
#pragma unroll
        for (int j = 0; j < 4; ++j) hv[j] = 0.5f * (a0[j] * inv0 + a1[j] * inv1) + bia[j];
        if (q == 0) {
            *(float4*)(hn + (size_t)v * 64 + 4 * k) = make_float4(hv[0], hv[1], hv[2], hv[3]);
#pragma unroll
            for (int j = 0; j < 4; ++j) { ps[j] += hv[j]; pq[j] += hv[j] * hv[j]; }
        }
    }
    __shared__ float sb[2][4][64];
    if (q == 0) {
#pragma unroll
        for (int j = 0; j < 4; ++j) { sb[0][wid][4 * k + j] = ps[j]; sb[1][wid][4 * k + j] = pq[j]; }
    }
    __syncthreads();
    int t = threadIdx.x;
    if (t < 64)
        atomicAdd(&bnsum[t], sb[0][0][t] + sb[0][1][t] + sb[0][2][t] + sb[0][3][t]);
    else if (t < 128)
        atomicAdd(&bnsum[64 + (t - 64)], sb[1][0][t - 64] + sb[1][1][t - 64] + sb[1][2][t - 64] + sb[1][3][t - 64]);
}

// ---------- BN param finalize ----------
__global__ void bn_final(const float* __restrict__ bnsum, const float* __restrict__ gamma,
                         const float* __restrict__ beta, float* __restrict__ scale, float* __restrict__ shift) {
    int c = threadIdx.x;
    if (c < 64) {
        float mu = bnsum[c] * (1.f / N_NODES);
        float ex2 = bnsum[64 + c] * (1.f / N_NODES);
        float var = ex2 - mu * mu;
        float sc = gamma[c] * rsqrtf(var + BN_EPS);
        scale[c] = sc;
        shift[c] = beta[c] - mu * sc;
    }
}

// ---------- pool (batch sorted): BN+ReLU on the fly, run-length local accumulation ----------
__global__ __launch_bounds__(256) void pool(const float* __restrict__ hn, const int* __restrict__ batch,
                                            const float* __restrict__ scale, const float* __restrict__ shift,
                                            float* __restrict__ gpool, float* __restrict__ gcnt) {
    int t = threadIdx.x;
    int c = t & 63, r = t >> 6;
    int base = blockIdx.x * 64;
    float acc = 0.f, cnt = 0.f;
    int curg = -1;
    for (int j = 0; j < 16; ++j) {
        int node = base + r * 16 + j;
        if (node >= N_NODES) break;
        int g = batch[node];
        float val = fmaxf(hn[(size_t)node * 64 + c] * scale[c] + shift[c], 0.f);
        if (g != curg) {
            if (curg >= 0) {
                atomicAdd(&gpool[curg * 64 + c], acc);
                if (c == 0) atomicAdd(&gcnt[curg], cnt);
            }
            curg = g; acc = 0.f; cnt = 0.f;
        }
        acc += val; cnt += 1.f;
    }
    if (curg >= 0) {
        atomicAdd(&gpool[curg * 64 + c], acc);
        if (c == 0) atomicAdd(&gcnt[curg], cnt);
    }
}

// ---------- classifier ----------
__global__ void classify(const float* __restrict__ gpool, const float* __restrict__ gcnt,
                         const float* __restrict__ Wc, const float* __restrict__ bc, float* __restrict__ out) {
    int t = threadIdx.x;
    if (t >= 640) return;
    int b = t / 10, o = t % 10;
    float inv = 1.f / fmaxf(gcnt[b], 1.f);
    float acc = 0.f;
    for (int c = 0; c < 64; ++c) acc += gpool[b * 64 + c] * Wc[c * 10 + o];
    out[t] = acc * inv + bc[o];
}

extern "C" void kernel_launch(void* const* d_in, const int* in_sizes, int n_in,
                              void* d_out, int out_size, void* d_ws, size_t ws_size,
                              hipStream_t stream) {
    (void)in_sizes; (void)n_in; (void)out_size; (void)ws_size;
    const float* x     = (const float*)d_in[0];
    const int*   ei    = (const int*)d_in[1];
    const int*   batch = (const int*)d_in[2];
    const float* W_enc = (const float*)d_in[3];
    const float* b_enc = (const float*)d_in[4];
    const float* Wl    = (const float*)d_in[5];
    const float* bl    = (const float*)d_in[6];
    const float* Wr    = (const float*)d_in[7];
    const float* br    = (const float*)d_in[8];
    const float* att   = (const float*)d_in[9];
    const float* bias  = (const float*)d_in[10];
    const float* gamma = (const float*)d_in[11];
    const float* beta  = (const float*)d_in[12];
    const float* Wc    = (const float*)d_in[13];
    const float* bc    = (const float*)d_in[14];
    float* out = (float*)d_out;

    char* ws = (char*)d_ws;
    size_t off = 0;
    auto A = [&](size_t bytes) { size_t r = off; off += (bytes + 255) & ~(size_t)255; return r; };
    int* row_ptr = (int*)(ws + A((N_NODES + 1) * 4));
    int* cursor  = (int*)(ws + A((size_t)N_NODES * 4));
    int* colv    = (int*)(ws + A((size_t)EP_EDGES * 4));
    int* bsum    = (int*)(ws + A(512));
    float* h     = (float*)(ws + A((size_t)N_NODES * 64 * 4));
    float* hn    = (float*)(ws + A((size_t)N_NODES * 64 * 4));
    unsigned short* xl = (unsigned short*)(ws + A((size_t)N_NODES * 128 * 2));
    unsigned short* xr = (unsigned short*)(ws + A((size_t)N_NODES * 128 * 2));
    float* bns     = (float*)(ws + A(2 * 128 * 4));
    float* bnscale = (float*)(ws + A(2 * 64 * 4));
    float* bnshift = (float*)(ws + A(2 * 64 * 4));
    float* gpool   = (float*)(ws + A(64 * 64 * 4));
    float* gcnt    = (float*)(ws + A(64 * 4));
    float* Wcl     = (float*)(ws + A(64 * 128 * 4));
    float* Wcr     = (float*)(ws + A(64 * 128 * 4));
    float* bcl     = (float*)(ws + A(128 * 4));
    float* bcr     = (float*)(ws + A(128 * 4));

    const int* srcv = ei;
    const int* dstv = ei + E_EDGES;

    hipMemsetAsync(cursor, 0, (size_t)N_NODES * 4, stream);
    hipMemsetAsync(bns, 0, 2 * 128 * 4, stream);
    hipMemsetAsync(gpool, 0, 64 * 64 * 4, stream);
    hipMemsetAsync(gcnt, 0, 64 * 4, stream);

    deg_count<<<(EP_EDGES + 255) / 256, 256, 0, stream>>>(dstv, cursor);
    scan_a<<<98, 1024, 0, stream>>>(cursor, row_ptr, bsum);
    scan_b<<<1, 64, 0, stream>>>(bsum, 98);
    scan_c<<<(N_NODES + 255) / 256, 256, 0, stream>>>(cursor, row_ptr, bsum);
    scatter_edges<<<(EP_EDGES + 255) / 256, 256, 0, stream>>>(srcv, dstv, cursor, colv);

    fuse_enc<<<1, 256, 0, stream>>>(W_enc, b_enc, Wl, bl, Wr, br, Wcl, bcl, Wcr, bcr);

    // layer 0 (encoder folded into weights; reads x directly)
    layer_gemm<0><<<1024, 256, 0, stream>>>(x, Wcl, bcl, Wcr, bcr, nullptr, nullptr, xl, xr);
    aggregate<<<2048, 256, 0, stream>>>((const uint4*)xl, (const uint4*)xr,
                                        row_ptr, colv, att, bias, hn, bns);
    bn_final<<<1, 64, 0, stream>>>(bns, gamma, beta, bnscale, bnshift);

    // layer 1
    layer_gemm<1><<<1024, 256, 0, stream>>>(hn, Wl + 64 * 128, bl + 128, Wr + 64 * 128, br + 128,
                                            bnscale, bnshift, xl, xr);
    aggregate<<<2048, 256, 0, stream>>>((const uint4*)xl, (const uint4*)xr,
                                        row_ptr, colv, att + 128, bias + 64, h, bns + 128);
    bn_final<<<1, 64, 0, stream>>>(bns + 128, gamma + 64, beta + 64, bnscale + 64, bnshift + 64);

    pool<<<(N_NODES + 63) / 64, 256, 0, stream>>>(h, batch, bnscale + 64, bnshift + 64, gpool, gcnt);
    classify<<<1, 640, 0, stream>>>(gpool, gcnt, Wc, bc, out);
}

// Round 3
// 653.710 us; speedup vs baseline: 1.5505x; 1.1169x over previous
//
#include <hip/hip_runtime.h>

#define N_NODES 100000
#define E_EDGES 1600000
#define EP_EDGES (E_EDGES + N_NODES)   // 1,700,000 with self loops
#define SLOPE 0.2f
#define BN_EPS 1e-5f
#define NB 8                 // dst buckets (one per XCD)
#define NODES_PER_B 12500
#define NREP 32              // sub-region replicas per bucket
#define SUBREG 8192          // edges per (rep,bucket) sub-region; mean 6640, +20 sigma

// ---------- helpers ----------
__device__ __forceinline__ float bflo(unsigned int u) { return __uint_as_float(u << 16); }
__device__ __forceinline__ float bfhi(unsigned int u) { return __uint_as_float(u & 0xffff0000u); }
__device__ __forceinline__ unsigned short f2bf(float f) {
    unsigned int u = __float_as_uint(f);
    unsigned int r = (u + 0x7fffu + ((u >> 16) & 1u)) >> 16;
    return (unsigned short)r;
}

// DPP rotate-reduce: sum across each 16-lane row, pure VALU (no LDS waits)
template <int CTRL>
__device__ __forceinline__ float dpp_add_step(float v) {
    int r = __builtin_amdgcn_update_dpp(0, __float_as_int(v), CTRL, 0xF, 0xF, false);
    return v + __int_as_float(r);
}
__device__ __forceinline__ float rowsum16(float v) {
    v = dpp_add_step<0x128>(v);   // row_ror:8
    v = dpp_add_step<0x124>(v);   // row_ror:4
    v = dpp_add_step<0x122>(v);   // row_ror:2
    v = dpp_add_step<0x121>(v);   // row_ror:1
    return v;
}

// ---------- bucketed CSR build ----------
// K3: scatter (src,dst) into (rep,bucket) sub-regions; wave-ballot ranking, 8 atomics/wave
__global__ __launch_bounds__(256) void bucket_scatter(const int* __restrict__ src, const int* __restrict__ dst,
                                                      int* __restrict__ gcur, unsigned long long* __restrict__ ebuf) {
    int i = blockIdx.x * 256 + threadIdx.x;
    int rep = blockIdx.x & (NREP - 1);
    bool active = i < EP_EDGES;
    int s = 0, d = 0;
    if (i < E_EDGES) { s = src[i]; d = dst[i]; }
    else if (active) { s = i - E_EDGES; d = s; }
    int b = active ? (int)((unsigned)d / NODES_PER_B) : NB;
    unsigned long long lt = (1ull << (threadIdx.x & 63)) - 1ull;
    int rank = 0;
    unsigned long long mymask = 0;
#pragma unroll
    for (int bb = 0; bb < NB; ++bb) {
        unsigned long long m = __ballot(b == bb);
        if (b == bb) { rank = __popcll(m & lt); mymask = m; }
    }
    int leader = mymask ? (__ffsll((long long)mymask) - 1) : 0;
    int lanebit = threadIdx.x & 63;
    int chunkbase = 0;
    if (active && lanebit == leader)
        chunkbase = atomicAdd(&gcur[rep * NB + b], (int)__popcll(mymask));
    chunkbase = __shfl(chunkbase, leader, 64);
    if (active)
        ebuf[(size_t)(rep * NB + b) * SUBREG + chunkbase + rank] =
            ((unsigned long long)(unsigned)d << 32) | (unsigned)s;
}

// K4: per-bucket degree histogram; blockIdx%8==bucket -> XCD-local atomics
__global__ __launch_bounds__(256) void bucket_deg(const int* __restrict__ gcur,
                                                  const unsigned long long* __restrict__ ebuf,
                                                  int* __restrict__ deg) {
    int b = blockIdx.x & (NB - 1), rep = blockIdx.x >> 3;
    int cnt = gcur[rep * NB + b];
    const unsigned long long* p = ebuf + (size_t)(rep * NB + b) * SUBREG;
    for (int i = threadIdx.x; i < cnt; i += 256) {
        int d = (int)(p[i] >> 32);
        atomicAdd(&deg[d], 1);
    }
}

// K6: fine scatter into CSR col; cursor+col writes XCD-local
__global__ __launch_bounds__(256) void bucket_fine(const int* __restrict__ gcur,
                                                   const unsigned long long* __restrict__ ebuf,
                                                   int* __restrict__ cursor, int* __restrict__ col) {
    int b = blockIdx.x & (NB - 1), rep = blockIdx.x >> 3;
    int cnt = gcur[rep * NB + b];
    const unsigned long long* p = ebuf + (size_t)(rep * NB + b) * SUBREG;
    for (int i = threadIdx.x; i < cnt; i += 256) {
        unsigned long long e = p[i];
        int d = (int)(e >> 32), s = (int)(e & 0xffffffffu);
        int pos = atomicAdd(&cursor[d], 1);
        col[pos] = s;
    }
}

// ---------- scans for row_ptr ----------
__global__ void scan_a(const int* __restrict__ deg, int* __restrict__ row_ptr, int* __restrict__ bsum) {
    __shared__ int tmp[1024];
    int tid = threadIdx.x;
    int i = blockIdx.x * 1024 + tid;
    int v = (i < N_NODES) ? deg[i] : 0;
    tmp[tid] = v; __syncthreads();
    for (int ofs = 1; ofs < 1024; ofs <<= 1) {
        int t2 = (tid >= ofs) ? tmp[tid - ofs] : 0;
        __syncthreads();
        tmp[tid] += t2;
        __syncthreads();
    }
    if (i < N_NODES) row_ptr[i + 1] = tmp[tid];
    if (tid == 1023) bsum[blockIdx.x] = tmp[1023];
}

__global__ void scan_b(int* __restrict__ bsum, int nb) {
    __shared__ int t[128];
    int i = threadIdx.x;
    int v = (i < nb) ? bsum[i] : 0;
    t[i] = v; __syncthreads();
    for (int o = 1; o < 128; o <<= 1) {
        int u = (i >= o) ? t[i - o] : 0;
        __syncthreads();
        t[i] += u;
        __syncthreads();
    }
    if (i < nb) bsum[i] = t[i] - v;   // exclusive
}

__global__ void scan_c(int* __restrict__ cursor, int* __restrict__ row_ptr, const int* __restrict__ bsum) {
    int i = blockIdx.x * 256 + threadIdx.x;
    if (i < N_NODES) {
        int d = cursor[i];
        int incl = row_ptr[i + 1] + bsum[i >> 10];
        row_ptr[i + 1] = incl;
        cursor[i] = incl - d;           // exclusive start
        if (i == 0) row_ptr[0] = 0;
    }
}

// ---------- fold encoder into layer-0 weights ----------
__global__ __launch_bounds__(256) void fuse_enc(const float* __restrict__ We, const float* __restrict__ be,
                                                const float* __restrict__ Wl, const float* __restrict__ bl,
                                                const float* __restrict__ Wr, const float* __restrict__ br,
                                                float* __restrict__ Wcl, float* __restrict__ bcl,
                                                float* __restrict__ Wcr, float* __restrict__ bcr) {
    __shared__ float sWe[64][64];   // sWe[m][k] = We[k][m]
    __shared__ float sbe[64];
    int t = threadIdx.x;
    for (int i = t; i < 4096; i += 256) sWe[i & 63][i >> 6] = We[i];
    if (t < 64) sbe[t] = be[t];
    __syncthreads();
    int j = t & 127, side = t >> 7;
    const float* W  = side ? Wr : Wl;
    const float* bb = side ? br : bl;
    float acc[64];
#pragma unroll
    for (int k = 0; k < 64; ++k) acc[k] = 0.f;
    float bacc = bb[j];
    for (int m = 0; m < 64; ++m) {
        float wv = W[m * 128 + j];
        bacc += sbe[m] * wv;
#pragma unroll
        for (int k = 0; k < 64; ++k) acc[k] += sWe[m][k] * wv;
    }
    float* Wc = side ? Wcr : Wcl;
#pragma unroll
    for (int k = 0; k < 64; ++k) Wc[k * 128 + j] = acc[k];
    (side ? bcr : bcl)[j] = bacc;
}

// ---------- per-layer transforms, packed bf16 (head1<<16)|head0 per channel ----------
template <int BN>
__global__ __launch_bounds__(256) void layer_gemm(const float* __restrict__ hin,
                                                  const float* __restrict__ Wl, const float* __restrict__ bl,
                                                  const float* __restrict__ Wr, const float* __restrict__ br,
                                                  const float* __restrict__ scale, const float* __restrict__ shift,
                                                  unsigned short* __restrict__ xl, unsigned short* __restrict__ xr) {
    int t = threadIdx.x;
    int tt = t & 127;
    bool isR = t >= 128;
    int c = tt >> 1, head = tt & 1;
    int colW = head * 64 + c;
    const float* W = isR ? Wr : Wl;
    float wcol[64];
#pragma unroll
    for (int k = 0; k < 64; ++k) wcol[k] = W[k * 128 + colW];
    float bj = (isR ? br : bl)[colW];
    unsigned short* dstp = isR ? xr : xl;
    __shared__ float sh[8][64];
    for (int base = blockIdx.x * 8; base < N_NODES; base += gridDim.x * 8) {
        __syncthreads();
        for (int i = t; i < 512; i += 256) {
            int node = base + (i >> 6);
            float v = (node < N_NODES) ? hin[(size_t)node * 64 + (i & 63)] : 0.f;
            if (BN) v = fmaxf(v * scale[i & 63] + shift[i & 63], 0.f);
            sh[i >> 6][i & 63] = v;
        }
        __syncthreads();
        int lim = min(8, N_NODES - base);
        for (int r = 0; r < lim; ++r) {
            float acc = bj;
            const float4* s4 = (const float4*)sh[r];
#pragma unroll
            for (int k4 = 0; k4 < 16; ++k4) {
                float4 v = s4[k4];
                acc += v.x * wcol[4 * k4] + v.y * wcol[4 * k4 + 1] + v.z * wcol[4 * k4 + 2] + v.w * wcol[4 * k4 + 3];
            }
            dstp[(size_t)(base + r) * 128 + tt] = f2bf(acc);
        }
    }
}

// ---------- fused GATv2 edge phase: DPP reduce, depth-2 prefetch ----------
__global__ __launch_bounds__(256) void aggregate(const char* __restrict__ xlb,
                                                 const uint4* __restrict__ xr4,
                                                 const int* __restrict__ row_ptr, const int* __restrict__ col,
                                                 const float* __restrict__ att_l, const float* __restrict__ bias_l,
                                                 float* __restrict__ hn, float* __restrict__ bnsum) {
    int lane = threadIdx.x & 63, wid = threadIdx.x >> 6;
    int q = lane >> 4, k = lane & 15;
    int koff = k << 4;
    // leaky(z) = 0.6z + 0.4|z|  (slope 0.2) with att pre-folded
    float a06h0[4], a04h0[4], a06h1[4], a04h1[4], bi[4];
#pragma unroll
    for (int j = 0; j < 4; ++j) {
        float A0 = att_l[4 * k + j], A1 = att_l[64 + 4 * k + j];
        a06h0[j] = 0.6f * A0; a04h0[j] = 0.4f * A0;
        a06h1[j] = 0.6f * A1; a04h1[j] = 0.4f * A1;
        bi[j] = bias_l[4 * k + j];
    }
    float ps[4] = {0, 0, 0, 0}, pq[4] = {0, 0, 0, 0};
    int w = blockIdx.x * 4 + wid, nw = gridDim.x * 4;
    for (int v = w; v < N_NODES; v += nw) {
        uint4 rp = xr4[(size_t)v * 16 + k];
        float r0[4] = {bflo(rp.x), bflo(rp.y), bflo(rp.z), bflo(rp.w)};
        float r1[4] = {bfhi(rp.x), bfhi(rp.y), bfhi(rp.z), bfhi(rp.w)};
        int beg = row_ptr[v], end = row_ptr[v + 1];
        float s0 = 0.f, s1 = 0.f;
        float a0[4] = {0, 0, 0, 0}, a1[4] = {0, 0, 0, 0};
        int cA = col[min(beg + q, end - 1)];
        uint4 lpA = *(const uint4*)(xlb + (((unsigned)cA) << 8) + koff);
        uint4 lpB = lpA;
        if (beg + 4 < end) {
            int cB = col[min(beg + 4 + q, end - 1)];
            lpB = *(const uint4*)(xlb + (((unsigned)cB) << 8) + koff);
        }
        for (int i = beg; i < end; i += 4) {
            uint4 lpC = lpB;
            if (i + 8 < end) {
                int cC = col[min(i + 8 + q, end - 1)];
                lpC = *(const uint4*)(xlb + (((unsigned)cC) << 8) + koff);
            }
            float l0[4] = {bflo(lpA.x), bflo(lpA.y), bflo(lpA.z), bflo(lpA.w)};
            float l1[4] = {bfhi(lpA.x), bfhi(lpA.y), bfhi(lpA.z), bfhi(lpA.w)};
            float t0 = 0.f, t1 = 0.f;
#pragma unroll
            for (int j = 0; j < 4; ++j) {
                float z0 = l0[j] + r0[j];
                float z1 = l1[j] + r1[j];
                t0 = fmaf(a06h0[j], z0, t0); t0 = fmaf(a04h0[j], fabsf(z0), t0);
                t1 = fmaf(a06h1[j], z1, t1); t1 = fmaf(a04h1[j], fabsf(z1), t1);
            }
            t0 = rowsum16(t0); t1 = rowsum16(t1);
            bool valid = (i + q) < end;
            float p0 = valid ? __expf(t0) : 0.f;
            float p1 = valid ? __expf(t1) : 0.f;
            s0 += p0; s1 += p1;
#pragma unroll
            for (int j = 0; j < 4; ++j) {
                a0[j] = fmaf(p0, l0[j], a0[j]);
                a1[j] = fmaf(p1, l1[j], a1[j]);
            }
            lpA = lpB; lpB = lpC;
        }
#pragma unroll
        for (int o = 16; o <= 32; o <<= 1) {
            s0 += __shfl_xor(s0, o, 64); s1 += __shfl_xor(s1, o, 64);
#pragma unroll
            for (int j = 0; j < 4; ++j) {
                a0[j] += __shfl_xor(a0[j], o, 64);
                a1[j] += __shfl_xor(a1[j], o, 64);
            }
        }
        if (q == 0) {
            float inv0 = 1.0f / s0, inv1 = 1.0f / s1;
            float hv[4];
#pragma unroll
            for (int j = 0; j < 4; ++j) hv[j] = 0.5f * (a0[j] * inv0 + a1[j] * inv1) + bi[j];
            *(float4*)(hn + (size_t)v * 64 + 4 * k) = make_float4(hv[0], hv[1], hv[2], hv[3]);
#pragma unroll
            for (int j = 0; j < 4; ++j) { ps[j] += hv[j]; pq[j] += hv[j] * hv[j]; }
        }
    }
    __shared__ float sb[2][4][64];
    if (q == 0) {
#pragma unroll
        for (int j = 0; j < 4; ++j) { sb[0][wid][4 * k + j] = ps[j]; sb[1][wid][4 * k + j] = pq[j]; }
    }
    __syncthreads();
    float* dstb = bnsum + (size_t)(blockIdx.x & 7) * 128;
    int t = threadIdx.x;
    if (t < 64)
        atomicAdd(&dstb[t], sb[0][0][t] + sb[0][1][t] + sb[0][2][t] + sb[0][3][t]);
    else if (t < 128)
        atomicAdd(&dstb[t], sb[1][0][t - 64] + sb[1][1][t - 64] + sb[1][2][t - 64] + sb[1][3][t - 64]);
}

// ---------- BN param finalize (8 replicas) ----------
__global__ void bn_final(const float* __restrict__ bnsum, const float* __restrict__ gamma,
                         const float* __restrict__ beta, float* __restrict__ scale, float* __restrict__ shift) {
    int c = threadIdx.x;
    if (c < 64) {
        float s = 0.f, sq = 0.f;
        for (int r = 0; r < 8; ++r) { s += bnsum[r * 128 + c]; sq += bnsum[r * 128 + 64 + c]; }
        float mu = s * (1.f / N_NODES);
        float ex2 = sq * (1.f / N_NODES);
        float var = ex2 - mu * mu;
        float sc = gamma[c] * rsqrtf(var + BN_EPS);
        scale[c] = sc;
        shift[c] = beta[c] - mu * sc;
    }
}

// ---------- pool (batch sorted) ----------
__global__ __launch_bounds__(256) void pool(const float* __restrict__ hn, const int* __restrict__ batch,
                                            const float* __restrict__ scale, const float* __restrict__ shift,
                                            float* __restrict__ gpool, float* __restrict__ gcnt) {
    int t = threadIdx.x;
    int c = t & 63, r = t >> 6;
    int base = blockIdx.x * 64;
    float acc = 0.f, cnt = 0.f;
    int curg = -1;
    for (int j = 0; j < 16; ++j) {
        int node = base + r * 16 + j;
        if (node >= N_NODES) break;
        int g = batch[node];
        float val = fmaxf(hn[(size_t)node * 64 + c] * scale[c] + shift[c], 0.f);
        if (g != curg) {
            if (curg >= 0) {
                atomicAdd(&gpool[curg * 64 + c], acc);
                if (c == 0) atomicAdd(&gcnt[curg], cnt);
            }
            curg = g; acc = 0.f; cnt = 0.f;
        }
        acc += val; cnt += 1.f;
    }
    if (curg >= 0) {
        atomicAdd(&gpool[curg * 64 + c], acc);
        if (c == 0) atomicAdd(&gcnt[curg], cnt);
    }
}

// ---------- classifier ----------
__global__ void classify(const float* __restrict__ gpool, const float* __restrict__ gcnt,
                         const float* __restrict__ Wc, const float* __restrict__ bc, float* __restrict__ out) {
    int t = threadIdx.x;
    if (t >= 640) return;
    int b = t / 10, o = t % 10;
    float inv = 1.f / fmaxf(gcnt[b], 1.f);
    float acc = 0.f;
    for (int c = 0; c < 64; ++c) acc += gpool[b * 64 + c] * Wc[c * 10 + o];
    out[t] = acc * inv + bc[o];
}

extern "C" void kernel_launch(void* const* d_in, const int* in_sizes, int n_in,
                              void* d_out, int out_size, void* d_ws, size_t ws_size,
                              hipStream_t stream) {
    (void)in_sizes; (void)n_in; (void)out_size; (void)ws_size;
    const float* x     = (const float*)d_in[0];
    const int*   ei    = (const int*)d_in[1];
    const int*   batch = (const int*)d_in[2];
    const float* W_enc = (const float*)d_in[3];
    const float* b_enc = (const float*)d_in[4];
    const float* Wl    = (const float*)d_in[5];
    const float* bl    = (const float*)d_in[6];
    const float* Wr    = (const float*)d_in[7];
    const float* br    = (const float*)d_in[8];
    const float* att   = (const float*)d_in[9];
    const float* bias  = (const float*)d_in[10];
    const float* gamma = (const float*)d_in[11];
    const float* beta  = (const float*)d_in[12];
    const float* Wc    = (const float*)d_in[13];
    const float* bc    = (const float*)d_in[14];
    float* out = (float*)d_out;

    char* ws = (char*)d_ws;
    size_t off = 0;
    auto A = [&](size_t bytes) { size_t r = off; off += (bytes + 255) & ~(size_t)255; return r; };
    int* row_ptr = (int*)(ws + A((N_NODES + 1) * 4));
    int* cursor  = (int*)(ws + A((size_t)N_NODES * 4));
    int* colv    = (int*)(ws + A((size_t)EP_EDGES * 4));
    int* bsum    = (int*)(ws + A(512));
    float* h     = (float*)(ws + A((size_t)N_NODES * 64 * 4));
    float* hn    = (float*)(ws + A((size_t)N_NODES * 64 * 4));
    unsigned short* xl = (unsigned short*)(ws + A((size_t)N_NODES * 128 * 2));
    unsigned short* xr = (unsigned short*)(ws + A((size_t)N_NODES * 128 * 2));
    float* bns     = (float*)(ws + A(2 * 8 * 128 * 4));
    float* bnscale = (float*)(ws + A(2 * 64 * 4));
    float* bnshift = (float*)(ws + A(2 * 64 * 4));
    float* gpool   = (float*)(ws + A(64 * 64 * 4));
    float* gcnt    = (float*)(ws + A(64 * 4));
    float* Wcl     = (float*)(ws + A(64 * 128 * 4));
    float* Wcr     = (float*)(ws + A(64 * 128 * 4));
    float* bcl     = (float*)(ws + A(128 * 4));
    float* bcr     = (float*)(ws + A(128 * 4));
    unsigned long long* ebuf = (unsigned long long*)(ws + A((size_t)NREP * NB * SUBREG * 8));
    int* gcur    = (int*)(ws + A(NREP * NB * 4));

    const int* srcv = ei;
    const int* dstv = ei + E_EDGES;

    hipMemsetAsync(cursor, 0, (size_t)N_NODES * 4, stream);
    hipMemsetAsync(gcur, 0, NREP * NB * 4, stream);
    hipMemsetAsync(bns, 0, 2 * 8 * 128 * 4, stream);
    hipMemsetAsync(gpool, 0, 64 * 64 * 4, stream);
    hipMemsetAsync(gcnt, 0, 64 * 4, stream);

    bucket_scatter<<<(EP_EDGES + 255) / 256, 256, 0, stream>>>(srcv, dstv, gcur, ebuf);
    bucket_deg<<<NREP * NB, 256, 0, stream>>>(gcur, ebuf, cursor);
    scan_a<<<98, 1024, 0, stream>>>(cursor, row_ptr, bsum);
    scan_b<<<1, 128, 0, stream>>>(bsum, 98);
    scan_c<<<(N_NODES + 255) / 256, 256, 0, stream>>>(cursor, row_ptr, bsum);
    bucket_fine<<<NREP * NB, 256, 0, stream>>>(gcur, ebuf, cursor, colv);

    fuse_enc<<<1, 256, 0, stream>>>(W_enc, b_enc, Wl, bl, Wr, br, Wcl, bcl, Wcr, bcr);

    // layer 0 (encoder folded into weights; reads x directly)
    layer_gemm<0><<<1024, 256, 0, stream>>>(x, Wcl, bcl, Wcr, bcr, nullptr, nullptr, xl, xr);
    aggregate<<<4096, 256, 0, stream>>>((const char*)xl, (const uint4*)xr,
                                        row_ptr, colv, att, bias, hn, bns);
    bn_final<<<1, 64, 0, stream>>>(bns, gamma, beta, bnscale, bnshift);

    // layer 1
    layer_gemm<1><<<1024, 256, 0, stream>>>(hn, Wl + 64 * 128, bl + 128, Wr + 64 * 128, br + 128,
                                            bnscale, bnshift, xl, xr);
    aggregate<<<4096, 256, 0, stream>>>((const char*)xl, (const uint4*)xr,
                                        row_ptr, colv, att + 128, bias + 64, h, bns + 1024);
    bn_final<<<1, 64, 0, stream>>>(bns + 1024, gamma + 64, beta + 64, bnscale + 64, bnshift + 64);

    pool<<<(N_NODES + 63) / 64, 256, 0, stream>>>(h, batch, bnscale + 64, bnshift + 64, gpool, gcnt);
    classify<<<1, 640, 0, stream>>>(gpool, gcnt, Wc, bc, out);
}

// Round 4
// 612.013 us; speedup vs baseline: 1.6562x; 1.0681x over previous
//
#include <hip/hip_runtime.h>

#define N_NODES 100000
#define E_EDGES 1600000
#define EP_EDGES (E_EDGES + N_NODES)   // 1,700,000 with self loops
#define SLOPE 0.2f
#define BN_EPS 1e-5f
#define NB 8                 // dst buckets (one per XCD)
#define NODES_PER_B 12500
#define NREP 32              // sub-region replicas per bucket
#define SUBREG 8192          // edges per (rep,bucket) sub-region

typedef _Float16 h2 __attribute__((ext_vector_type(2)));

#if defined(__has_builtin)
#if __has_builtin(__builtin_amdgcn_fdot2)
#define HAVE_FDOT2 1
#endif
#endif

__device__ __forceinline__ float fdot2f(h2 a, h2 b, float c) {
#ifdef HAVE_FDOT2
    return __builtin_amdgcn_fdot2(a, b, c, false);
#else
    return c + (float)a[0] * (float)b[0] + (float)a[1] * (float)b[1];
#endif
}
__device__ __forceinline__ h2 bch2(unsigned u) { return __builtin_bit_cast(h2, u); }
__device__ __forceinline__ h2 habs2(h2 z) {
    return __builtin_bit_cast(h2, (unsigned)(__builtin_bit_cast(unsigned, z) & 0x7fff7fffu));
}
__device__ __forceinline__ h2 shflx_h2(h2 a, int o) {
    return __builtin_bit_cast(h2, __shfl_xor(__builtin_bit_cast(int, a), o, 64));
}

// DPP rotate-reduce: sum across each 16-lane row, pure VALU
template <int CTRL>
__device__ __forceinline__ float dpp_add_step(float v) {
    int r = __builtin_amdgcn_update_dpp(0, __float_as_int(v), CTRL, 0xF, 0xF, false);
    return v + __int_as_float(r);
}
__device__ __forceinline__ float rowsum16(float v) {
    v = dpp_add_step<0x128>(v);
    v = dpp_add_step<0x124>(v);
    v = dpp_add_step<0x122>(v);
    v = dpp_add_step<0x121>(v);
    return v;
}

// ---------- bucketed CSR build ----------
__global__ __launch_bounds__(256) void bucket_scatter(const int* __restrict__ src, const int* __restrict__ dst,
                                                      int* __restrict__ gcur, unsigned long long* __restrict__ ebuf) {
    int i = blockIdx.x * 256 + threadIdx.x;
    int rep = blockIdx.x & (NREP - 1);
    bool active = i < EP_EDGES;
    int s = 0, d = 0;
    if (i < E_EDGES) { s = src[i]; d = dst[i]; }
    else if (active) { s = i - E_EDGES; d = s; }
    int b = active ? (int)((unsigned)d / NODES_PER_B) : NB;
    unsigned long long lt = (1ull << (threadIdx.x & 63)) - 1ull;
    int rank = 0;
    unsigned long long mymask = 0;
#pragma unroll
    for (int bb = 0; bb < NB; ++bb) {
        unsigned long long m = __ballot(b == bb);
        if (b == bb) { rank = __popcll(m & lt); mymask = m; }
    }
    int leader = mymask ? (__ffsll((long long)mymask) - 1) : 0;
    int lanebit = threadIdx.x & 63;
    int chunkbase = 0;
    if (active && lanebit == leader)
        chunkbase = atomicAdd(&gcur[rep * NB + b], (int)__popcll(mymask));
    chunkbase = __shfl(chunkbase, leader, 64);
    if (active)
        ebuf[(size_t)(rep * NB + b) * SUBREG + chunkbase + rank] =
            ((unsigned long long)(unsigned)d << 32) | (unsigned)s;
}

// LDS-histogram degree count per (rep,bucket)
__global__ __launch_bounds__(256) void bucket_deg(const int* __restrict__ gcur,
                                                  const unsigned long long* __restrict__ ebuf,
                                                  int* __restrict__ deg) {
    __shared__ int ldeg[NODES_PER_B];
    int b = blockIdx.x & (NB - 1), rep = blockIdx.x >> 3;
    for (int j = threadIdx.x; j < NODES_PER_B; j += 256) ldeg[j] = 0;
    __syncthreads();
    int cnt = gcur[rep * NB + b];
    int base = b * NODES_PER_B;
    const unsigned long long* p = ebuf + (size_t)(rep * NB + b) * SUBREG;
    for (int i = threadIdx.x; i < cnt; i += 256)
        atomicAdd(&ldeg[(int)(p[i] >> 32) - base], 1);
    __syncthreads();
    for (int j = threadIdx.x; j < NODES_PER_B; j += 256) {
        int v = ldeg[j];
        if (v) atomicAdd(&deg[base + j], v);
    }
}

__global__ __launch_bounds__(256) void bucket_fine(const int* __restrict__ gcur,
                                                   const unsigned long long* __restrict__ ebuf,
                                                   int* __restrict__ cursor, int* __restrict__ col) {
    int b = blockIdx.x & (NB - 1), rep = blockIdx.x >> 3;
    int cnt = gcur[rep * NB + b];
    const unsigned long long* p = ebuf + (size_t)(rep * NB + b) * SUBREG;
    for (int i = threadIdx.x; i < cnt; i += 256) {
        unsigned long long e = p[i];
        int d = (int)(e >> 32), s = (int)(e & 0xffffffffu);
        int pos = atomicAdd(&cursor[d], 1);
        col[pos] = s;
    }
}

// ---------- scans for row_ptr ----------
__global__ void scan_a(const int* __restrict__ deg, int* __restrict__ row_ptr, int* __restrict__ bsum) {
    __shared__ int tmp[1024];
    int tid = threadIdx.x;
    int i = blockIdx.x * 1024 + tid;
    int v = (i < N_NODES) ? deg[i] : 0;
    tmp[tid] = v; __syncthreads();
    for (int ofs = 1; ofs < 1024; ofs <<= 1) {
        int t2 = (tid >= ofs) ? tmp[tid - ofs] : 0;
        __syncthreads();
        tmp[tid] += t2;
        __syncthreads();
    }
    if (i < N_NODES) row_ptr[i + 1] = tmp[tid];
    if (tid == 1023) bsum[blockIdx.x] = tmp[1023];
}

// scan_c with inline block-sum prefix (scan_b folded in)
__global__ void scan_c(int* __restrict__ cursor, int* __restrict__ row_ptr, const int* __restrict__ bsum) {
    __shared__ int sp[128];
    int t = threadIdx.x;
    if (t < 128) sp[t] = (t < 98) ? bsum[t] : 0;
    __syncthreads();
    for (int o = 1; o < 128; o <<= 1) {
        int v = (t < 128 && t >= o) ? sp[t - o] : 0;
        __syncthreads();
        if (t < 128) sp[t] += v;
        __syncthreads();
    }
    int i = blockIdx.x * 256 + t;
    if (i < N_NODES) {
        int d = cursor[i];
        int blk = i >> 10;
        int pre = blk ? sp[blk - 1] : 0;
        int incl = row_ptr[i + 1] + pre;
        row_ptr[i + 1] = incl;
        cursor[i] = incl - d;           // exclusive start
        if (i == 0) row_ptr[0] = 0;
    }
}

// ---------- fold encoder into layer-0 weights ----------
__global__ __launch_bounds__(256) void fuse_enc(const float* __restrict__ We, const float* __restrict__ be,
                                                const float* __restrict__ Wl, const float* __restrict__ bl,
                                                const float* __restrict__ Wr, const float* __restrict__ br,
                                                float* __restrict__ Wcl, float* __restrict__ bcl,
                                                float* __restrict__ Wcr, float* __restrict__ bcr) {
    __shared__ float sWe[64][64];   // sWe[m][k] = We[k][m]
    __shared__ float sbe[64];
    int t = threadIdx.x;
    for (int i = t; i < 4096; i += 256) sWe[i & 63][i >> 6] = We[i];
    if (t < 64) sbe[t] = be[t];
    __syncthreads();
    int j = t & 127, side = t >> 7;
    const float* W  = side ? Wr : Wl;
    const float* bb = side ? br : bl;
    float acc[64];
#pragma unroll
    for (int k = 0; k < 64; ++k) acc[k] = 0.f;
    float bacc = bb[j];
    for (int m = 0; m < 64; ++m) {
        float wv = W[m * 128 + j];
        bacc += sbe[m] * wv;
#pragma unroll
        for (int k = 0; k < 64; ++k) acc[k] += sWe[m][k] * wv;
    }
    float* Wc = side ? Wcr : Wcl;
#pragma unroll
    for (int k = 0; k < 64; ++k) Wc[k * 128 + j] = acc[k];
    (side ? bcr : bcl)[j] = bacc;
}

// ---------- per-layer transforms, f16 head-interleaved chunks ----------
// node chunk k (16B): [h0 c4k..4k+3 | h1 c4k..4k+3], element idx = (c>>2)*8 + head*4 + (c&3)
template <int BN>
__global__ __launch_bounds__(256) void layer_gemm(const float* __restrict__ hin,
                                                  const float* __restrict__ Wl, const float* __restrict__ bl,
                                                  const float* __restrict__ Wr, const float* __restrict__ br,
                                                  const float* __restrict__ bns, const float* __restrict__ gamma,
                                                  const float* __restrict__ beta,
                                                  unsigned short* __restrict__ xl, unsigned short* __restrict__ xr) {
    __shared__ float ssc[64], ssh[64];
    int t = threadIdx.x;
    if (BN) {
        if (t < 64) {
            float s = 0.f, sq = 0.f;
#pragma unroll
            for (int r = 0; r < 8; ++r) { s += bns[r * 128 + t]; sq += bns[r * 128 + 64 + t]; }
            float mu = s * (1.f / N_NODES);
            float var = sq * (1.f / N_NODES) - mu * mu;
            float sc = gamma[t] * rsqrtf(var + BN_EPS);
            ssc[t] = sc; ssh[t] = beta[t] - mu * sc;
        }
        __syncthreads();
    }
    int tt = t & 127;
    bool isR = t >= 128;
    int c = tt >> 1, head = tt & 1;
    int colW = head * 64 + c;
    int oidx = (c >> 2) * 8 + head * 4 + (c & 3);
    const float* W = isR ? Wr : Wl;
    float wcol[64];
#pragma unroll
    for (int k = 0; k < 64; ++k) wcol[k] = W[k * 128 + colW];
    float bj = (isR ? br : bl)[colW];
    unsigned short* dstp = isR ? xr : xl;
    __shared__ float sh[8][64];
    for (int base = blockIdx.x * 8; base < N_NODES; base += gridDim.x * 8) {
        __syncthreads();
        for (int i = t; i < 512; i += 256) {
            int node = base + (i >> 6);
            float v = (node < N_NODES) ? hin[(size_t)node * 64 + (i & 63)] : 0.f;
            if (BN) v = fmaxf(v * ssc[i & 63] + ssh[i & 63], 0.f);
            sh[i >> 6][i & 63] = v;
        }
        __syncthreads();
        int lim = min(8, N_NODES - base);
        for (int r = 0; r < lim; ++r) {
            float acc = bj;
            const float4* s4 = (const float4*)sh[r];
#pragma unroll
            for (int k4 = 0; k4 < 16; ++k4) {
                float4 v = s4[k4];
                acc += v.x * wcol[4 * k4] + v.y * wcol[4 * k4 + 1] + v.z * wcol[4 * k4 + 2] + v.w * wcol[4 * k4 + 3];
            }
            dstp[(size_t)(base + r) * 128 + oidx] = __builtin_bit_cast(unsigned short, (_Float16)acc);
        }
    }
}

// ---------- fused GATv2 edge phase: packed-f16 math, 3-deep col / 2-deep gather pipeline ----------
__global__ __launch_bounds__(256) void aggregate(const char* __restrict__ xlb,
                                                 const uint4* __restrict__ xr4,
                                                 const int* __restrict__ row_ptr, const int* __restrict__ col,
                                                 const float* __restrict__ att_l, const float* __restrict__ bias_l,
                                                 float* __restrict__ hn, float* __restrict__ bnsum) {
    int lane = threadIdx.x & 63, wid = threadIdx.x >> 6;
    int q = lane >> 4, k = lane & 15;
    int koff = k << 4;
    h2 atA0 = {(_Float16)att_l[4 * k], (_Float16)att_l[4 * k + 1]};
    h2 atA1 = {(_Float16)att_l[4 * k + 2], (_Float16)att_l[4 * k + 3]};
    h2 atB0 = {(_Float16)att_l[64 + 4 * k], (_Float16)att_l[64 + 4 * k + 1]};
    h2 atB1 = {(_Float16)att_l[64 + 4 * k + 2], (_Float16)att_l[64 + 4 * k + 3]};
    float bi0 = bias_l[4 * k], bi1 = bias_l[4 * k + 1], bi2 = bias_l[4 * k + 2], bi3 = bias_l[4 * k + 3];
    const h2 c06 = {(_Float16)0.6f, (_Float16)0.6f};
    const h2 c04 = {(_Float16)0.4f, (_Float16)0.4f};
    float ps[4] = {0, 0, 0, 0}, pq[4] = {0, 0, 0, 0};
    int w = blockIdx.x * 4 + wid, nw = gridDim.x * 4;
    for (int v = w; v < N_NODES; v += nw) {
        uint4 rp = xr4[(size_t)v * 16 + k];
        h2 rA0 = bch2(rp.x), rA1 = bch2(rp.y), rB0 = bch2(rp.z), rB1 = bch2(rp.w);
        int beg = row_ptr[v], end = row_ptr[v + 1];
        float s0 = 0.f, s1 = 0.f;
        h2 aA0 = {0, 0}, aA1 = {0, 0}, aB0 = {0, 0}, aB1 = {0, 0};
        const int* cptr = col + beg + q;      // padded: safe to over-read 32 entries
        int cv0 = cptr[0], cv1 = cptr[4], cv2 = cptr[8], cv3 = cptr[12];
        cptr += 16;
        uint4 lp0 = *(const uint4*)(xlb + (((size_t)(unsigned)cv0) << 8) + koff);
        uint4 lp1 = *(const uint4*)(xlb + (((size_t)(unsigned)cv1) << 8) + koff);
#pragma unroll 2
        for (int i = beg; i < end; i += 4) {
            uint4 lp2 = *(const uint4*)(xlb + (((size_t)(unsigned)cv2) << 8) + koff);
            cv2 = cv3;
            cv3 = *cptr; cptr += 4;
            h2 lA0 = bch2(lp0.x), lA1 = bch2(lp0.y), lB0 = bch2(lp0.z), lB1 = bch2(lp0.w);
            h2 zA0 = lA0 + rA0, zA1 = lA1 + rA1, zB0 = lB0 + rB0, zB1 = lB1 + rB1;
            h2 yA0 = zA0 * c06 + habs2(zA0) * c04;
            h2 yA1 = zA1 * c06 + habs2(zA1) * c04;
            h2 yB0 = zB0 * c06 + habs2(zB0) * c04;
            h2 yB1 = zB1 * c06 + habs2(zB1) * c04;
            float t0 = fdot2f(yA1, atA1, fdot2f(yA0, atA0, 0.f));
            float t1 = fdot2f(yB1, atB1, fdot2f(yB0, atB0, 0.f));
            t0 = rowsum16(t0); t1 = rowsum16(t1);
            bool valid = (i + q) < end;
            float p0 = valid ? __expf(t0) : 0.f;
            float p1 = valid ? __expf(t1) : 0.f;
            s0 += p0; s1 += p1;
            h2 p0h = {(_Float16)p0, (_Float16)p0};
            h2 p1h = {(_Float16)p1, (_Float16)p1};
            aA0 += p0h * lA0; aA1 += p0h * lA1;
            aB0 += p1h * lB0; aB1 += p1h * lB1;
            lp0 = lp1; lp1 = lp2;
        }
#pragma unroll
        for (int o = 16; o <= 32; o <<= 1) {
            s0 += __shfl_xor(s0, o, 64); s1 += __shfl_xor(s1, o, 64);
            aA0 += shflx_h2(aA0, o); aA1 += shflx_h2(aA1, o);
            aB0 += shflx_h2(aB0, o); aB1 += shflx_h2(aB1, o);
        }
        if (q == 0) {
            float i0 = 0.5f / s0, i1 = 0.5f / s1;
            float hv0 = (float)aA0[0] * i0 + (float)aB0[0] * i1 + bi0;
            float hv1 = (float)aA0[1] * i0 + (float)aB0[1] * i1 + bi1;
            float hv2 = (float)aA1[0] * i0 + (float)aB1[0] * i1 + bi2;
            float hv3 = (float)aA1[1] * i0 + (float)aB1[1] * i1 + bi3;
            *(float4*)(hn + (size_t)v * 64 + 4 * k) = make_float4(hv0, hv1, hv2, hv3);
            ps[0] += hv0; pq[0] += hv0 * hv0;
            ps[1] += hv1; pq[1] += hv1 * hv1;
            ps[2] += hv2; pq[2] += hv2 * hv2;
            ps[3] += hv3; pq[3] += hv3 * hv3;
        }
    }
    __shared__ float sb[2][4][64];
    if (q == 0) {
#pragma unroll
        for (int j = 0; j < 4; ++j) { sb[0][wid][4 * k + j] = ps[j]; sb[1][wid][4 * k + j] = pq[j]; }
    }
    __syncthreads();
    float* dstb = bnsum + (size_t)(blockIdx.x & 7) * 128;
    int t = threadIdx.x;
    if (t < 64)
        atomicAdd(&dstb[t], sb[0][0][t] + sb[0][1][t] + sb[0][2][t] + sb[0][3][t]);
    else if (t < 128)
        atomicAdd(&dstb[t], sb[1][0][t - 64] + sb[1][1][t - 64] + sb[1][2][t - 64] + sb[1][3][t - 64]);
}

// ---------- pool + BN finalize + classifier (last-block) ----------
__global__ __launch_bounds__(256) void pool_cls(const float* __restrict__ hn, const int* __restrict__ batch,
                                                const float* __restrict__ bns, const float* __restrict__ gamma,
                                                const float* __restrict__ beta,
                                                const float* __restrict__ Wc, const float* __restrict__ bcb,
                                                float* __restrict__ gpool, float* __restrict__ gcnt,
                                                int* __restrict__ pcount, float* __restrict__ out) {
    __shared__ float ssc[64], ssh[64];
    __shared__ int lastf;
    int t = threadIdx.x;
    if (t < 64) {
        float s = 0.f, sq = 0.f;
#pragma unroll
        for (int r = 0; r < 8; ++r) { s += bns[r * 128 + t]; sq += bns[r * 128 + 64 + t]; }
        float mu = s * (1.f / N_NODES);
        float var = sq * (1.f / N_NODES) - mu * mu;
        float sc = gamma[t] * rsqrtf(var + BN_EPS);
        ssc[t] = sc; ssh[t] = beta[t] - mu * sc;
    }
    __syncthreads();
    int c = t & 63, r = t >> 6;
    int base = blockIdx.x * 64;
    float acc = 0.f, cnt = 0.f;
    int curg = -1;
    for (int j = 0; j < 16; ++j) {
        int node = base + r * 16 + j;
        if (node >= N_NODES) break;
        int g = batch[node];
        float val = fmaxf(hn[(size_t)node * 64 + c] * ssc[c] + ssh[c], 0.f);
        if (g != curg) {
            if (curg >= 0) {
                atomicAdd(&gpool[curg * 64 + c], acc);
                if (c == 0) atomicAdd(&gcnt[curg], cnt);
            }
            curg = g; acc = 0.f; cnt = 0.f;
        }
        acc += val; cnt += 1.f;
    }
    if (curg >= 0) {
        atomicAdd(&gpool[curg * 64 + c], acc);
        if (c == 0) atomicAdd(&gcnt[curg], cnt);
    }
    __threadfence();
    __syncthreads();
    if (t == 0) lastf = (atomicAdd(pcount, 1) == (int)gridDim.x - 1);
    __syncthreads();
    if (lastf) {
        __threadfence();
        for (int i = t; i < 640; i += 256) {
            int b = i / 10, o = i % 10;
            float inv = 1.f / fmaxf(gcnt[b], 1.f);
            float a = 0.f;
            for (int cc = 0; cc < 64; ++cc) a += gpool[b * 64 + cc] * Wc[cc * 10 + o];
            out[i] = a * inv + bcb[o];
        }
    }
}

extern "C" void kernel_launch(void* const* d_in, const int* in_sizes, int n_in,
                              void* d_out, int out_size, void* d_ws, size_t ws_size,
                              hipStream_t stream) {
    (void)in_sizes; (void)n_in; (void)out_size; (void)ws_size;
    const float* x     = (const float*)d_in[0];
    const int*   ei    = (const int*)d_in[1];
    const int*   batch = (const int*)d_in[2];
    const float* W_enc = (const float*)d_in[3];
    const float* b_enc = (const float*)d_in[4];
    const float* Wl    = (const float*)d_in[5];
    const float* bl    = (const float*)d_in[6];
    const float* Wr    = (const float*)d_in[7];
    const float* br    = (const float*)d_in[8];
    const float* att   = (const float*)d_in[9];
    const float* bias  = (const float*)d_in[10];
    const float* gamma = (const float*)d_in[11];
    const float* beta  = (const float*)d_in[12];
    const float* Wc    = (const float*)d_in[13];
    const float* bc    = (const float*)d_in[14];
    float* out = (float*)d_out;

    char* ws = (char*)d_ws;
    size_t off = 0;
    auto A = [&](size_t bytes) { size_t r = off; off += (bytes + 255) & ~(size_t)255; return r; };

    int* row_ptr = (int*)(ws + A((N_NODES + 1) * 4));
    // colv followed immediately by the contiguous zero region (one memset)
    size_t colv_off = A((size_t)EP_EDGES * 4 + 426240);
    int* colv = (int*)(ws + colv_off);
    char* zbase = ws + colv_off + (size_t)EP_EDGES * 4;
    // zero-region layout
    int*   cursor = (int*)(zbase + 128);              // 400000 B  (col pad = zbase+0, 128 B)
    int*   gcur   = (int*)(zbase + 400128);           // 1024 B
    float* bns    = (float*)(zbase + 401152);         // 8192 B (2 layers x 8 reps x 128)
    float* gpool  = (float*)(zbase + 409344);         // 16384 B
    float* gcnt   = (float*)(zbase + 425728);         // 256 B
    int*   pcount = (int*)(zbase + 425984);           // 256 B
    const size_t ZBYTES = 426240;

    float* h   = (float*)(ws + A((size_t)N_NODES * 64 * 4));
    float* hn  = (float*)(ws + A((size_t)N_NODES * 64 * 4));
    unsigned short* xl = (unsigned short*)(ws + A((size_t)N_NODES * 128 * 2));
    unsigned short* xr = (unsigned short*)(ws + A((size_t)N_NODES * 128 * 2));
    unsigned long long* ebuf = (unsigned long long*)(ws + A((size_t)NREP * NB * SUBREG * 8));
    int* bsum  = (int*)(ws + A(512));
    float* Wcl = (float*)(ws + A(64 * 128 * 4));
    float* Wcr = (float*)(ws + A(64 * 128 * 4));
    float* bcl = (float*)(ws + A(128 * 4));
    float* bcr = (float*)(ws + A(128 * 4));

    const int* srcv = ei;
    const int* dstv = ei + E_EDGES;

    hipMemsetAsync(zbase, 0, ZBYTES, stream);

    bucket_scatter<<<(EP_EDGES + 255) / 256, 256, 0, stream>>>(srcv, dstv, gcur, ebuf);
    bucket_deg<<<NREP * NB, 256, 0, stream>>>(gcur, ebuf, cursor);
    scan_a<<<98, 1024, 0, stream>>>(cursor, row_ptr, bsum);
    scan_c<<<(N_NODES + 255) / 256, 256, 0, stream>>>(cursor, row_ptr, bsum);
    bucket_fine<<<NREP * NB, 256, 0, stream>>>(gcur, ebuf, cursor, colv);

    fuse_enc<<<1, 256, 0, stream>>>(W_enc, b_enc, Wl, bl, Wr, br, Wcl, bcl, Wcr, bcr);

    // layer 0 (encoder folded; reads x directly)
    layer_gemm<0><<<1024, 256, 0, stream>>>(x, Wcl, bcl, Wcr, bcr, bns, gamma, beta, xl, xr);
    aggregate<<<2048, 256, 0, stream>>>((const char*)xl, (const uint4*)xr,
                                        row_ptr, colv, att, bias, hn, bns);
    // layer 1 (BN of layer 0 folded into prologue)
    layer_gemm<1><<<1024, 256, 0, stream>>>(hn, Wl + 64 * 128, bl + 128, Wr + 64 * 128, br + 128,
                                            bns, gamma, beta, xl, xr);
    aggregate<<<2048, 256, 0, stream>>>((const char*)xl, (const uint4*)xr,
                                        row_ptr, colv, att + 128, bias + 64, h, bns + 1024);

    // pool + BN(layer1) + classifier fused
    pool_cls<<<(N_NODES + 63) / 64, 256, 0, stream>>>(h, batch, bns + 1024, gamma + 64, beta + 64,
                                                      Wc, bc, gpool, gcnt, pcount, out);
}

// Round 5
// 537.557 us; speedup vs baseline: 1.8856x; 1.1385x over previous
//
#include <hip/hip_runtime.h>

#define N_NODES 100000
#define E_EDGES 1600000
#define EP_EDGES (E_EDGES + N_NODES)   // 1,700,000 with self loops
#define SLOPE 0.2f
#define BN_EPS 1e-5f
#define NB 8                 // dst buckets (one per XCD)
#define NODES_PER_B 12500
#define NREP 32              // sub-region replicas per bucket
#define SUBREG 8192          // edges per (rep,bucket) sub-region

typedef _Float16 h2 __attribute__((ext_vector_type(2)));

#if defined(__has_builtin)
#if __has_builtin(__builtin_amdgcn_fdot2)
#define HAVE_FDOT2 1
#endif
#endif

__device__ __forceinline__ float fdot2f(h2 a, h2 b, float c) {
#ifdef HAVE_FDOT2
    return __builtin_amdgcn_fdot2(a, b, c, false);
#else
    return c + (float)a[0] * (float)b[0] + (float)a[1] * (float)b[1];
#endif
}
__device__ __forceinline__ h2 bch2(unsigned u) { return __builtin_bit_cast(h2, u); }
__device__ __forceinline__ h2 habs2(h2 z) {
    return __builtin_bit_cast(h2, (unsigned)(__builtin_bit_cast(unsigned, z) & 0x7fff7fffu));
}
__device__ __forceinline__ h2 shflx_h2(h2 a, int o) {
    return __builtin_bit_cast(h2, __shfl_xor(__builtin_bit_cast(int, a), o, 64));
}

// DPP rotate-reduce: sum across each 16-lane row, pure VALU
template <int CTRL>
__device__ __forceinline__ float dpp_add_step(float v) {
    int r = __builtin_amdgcn_update_dpp(0, __float_as_int(v), CTRL, 0xF, 0xF, false);
    return v + __int_as_float(r);
}
__device__ __forceinline__ float rowsum16(float v) {
    v = dpp_add_step<0x128>(v);
    v = dpp_add_step<0x124>(v);
    v = dpp_add_step<0x122>(v);
    v = dpp_add_step<0x121>(v);
    return v;
}

// ---------- bucketed CSR build ----------
__global__ __launch_bounds__(256) void bucket_scatter(const int* __restrict__ src, const int* __restrict__ dst,
                                                      int* __restrict__ gcur, unsigned long long* __restrict__ ebuf) {
    int i = blockIdx.x * 256 + threadIdx.x;
    int rep = blockIdx.x & (NREP - 1);
    bool active = i < EP_EDGES;
    int s = 0, d = 0;
    if (i < E_EDGES) { s = src[i]; d = dst[i]; }
    else if (active) { s = i - E_EDGES; d = s; }
    int b = active ? (int)((unsigned)d / NODES_PER_B) : NB;
    unsigned long long lt = (1ull << (threadIdx.x & 63)) - 1ull;
    int rank = 0;
    unsigned long long mymask = 0;
#pragma unroll
    for (int bb = 0; bb < NB; ++bb) {
        unsigned long long m = __ballot(b == bb);
        if (b == bb) { rank = __popcll(m & lt); mymask = m; }
    }
    int leader = mymask ? (__ffsll((long long)mymask) - 1) : 0;
    int lanebit = threadIdx.x & 63;
    int chunkbase = 0;
    if (active && lanebit == leader)
        chunkbase = atomicAdd(&gcur[rep * NB + b], (int)__popcll(mymask));
    chunkbase = __shfl(chunkbase, leader, 64);
    if (active)
        ebuf[(size_t)(rep * NB + b) * SUBREG + chunkbase + rank] =
            ((unsigned long long)(unsigned)d << 32) | (unsigned)s;
}

// LDS-histogram degree count per (rep,bucket)
__global__ __launch_bounds__(256) void bucket_deg(const int* __restrict__ gcur,
                                                  const unsigned long long* __restrict__ ebuf,
                                                  int* __restrict__ deg) {
    __shared__ int ldeg[NODES_PER_B];
    int b = blockIdx.x & (NB - 1), rep = blockIdx.x >> 3;
    for (int j = threadIdx.x; j < NODES_PER_B; j += 256) ldeg[j] = 0;
    __syncthreads();
    int cnt = gcur[rep * NB + b];
    int base = b * NODES_PER_B;
    const unsigned long long* p = ebuf + (size_t)(rep * NB + b) * SUBREG;
    for (int i = threadIdx.x; i < cnt; i += 256)
        atomicAdd(&ldeg[(int)(p[i] >> 32) - base], 1);
    __syncthreads();
    for (int j = threadIdx.x; j < NODES_PER_B; j += 256) {
        int v = ldeg[j];
        if (v) atomicAdd(&deg[base + j], v);
    }
}

__global__ __launch_bounds__(256) void bucket_fine(const int* __restrict__ gcur,
                                                   const unsigned long long* __restrict__ ebuf,
                                                   int* __restrict__ cursor, int* __restrict__ col) {
    int b = blockIdx.x & (NB - 1), rep = blockIdx.x >> 3;
    int cnt = gcur[rep * NB + b];
    const unsigned long long* p = ebuf + (size_t)(rep * NB + b) * SUBREG;
    for (int i = threadIdx.x; i < cnt; i += 256) {
        unsigned long long e = p[i];
        int d = (int)(e >> 32), s = (int)(e & 0xffffffffu);
        int pos = atomicAdd(&cursor[d], 1);
        col[pos] = s;
    }
}

// ---------- scans for row_ptr ----------
__global__ void scan_a(const int* __restrict__ deg, int* __restrict__ row_ptr, int* __restrict__ bsum) {
    __shared__ int tmp[1024];
    int tid = threadIdx.x;
    int i = blockIdx.x * 1024 + tid;
    int v = (i < N_NODES) ? deg[i] : 0;
    tmp[tid] = v; __syncthreads();
    for (int ofs = 1; ofs < 1024; ofs <<= 1) {
        int t2 = (tid >= ofs) ? tmp[tid - ofs] : 0;
        __syncthreads();
        tmp[tid] += t2;
        __syncthreads();
    }
    if (i < N_NODES) row_ptr[i + 1] = tmp[tid];
    if (tid == 1023) bsum[blockIdx.x] = tmp[1023];
}

// scan_c with inline block-sum prefix (scan_b folded in)
__global__ void scan_c(int* __restrict__ cursor, int* __restrict__ row_ptr, const int* __restrict__ bsum) {
    __shared__ int sp[128];
    int t = threadIdx.x;
    if (t < 128) sp[t] = (t < 98) ? bsum[t] : 0;
    __syncthreads();
    for (int o = 1; o < 128; o <<= 1) {
        int v = (t < 128 && t >= o) ? sp[t - o] : 0;
        __syncthreads();
        if (t < 128) sp[t] += v;
        __syncthreads();
    }
    int i = blockIdx.x * 256 + t;
    if (i < N_NODES) {
        int d = cursor[i];
        int blk = i >> 10;
        int pre = blk ? sp[blk - 1] : 0;
        int incl = row_ptr[i + 1] + pre;
        row_ptr[i + 1] = incl;
        cursor[i] = incl - d;           // exclusive start
        if (i == 0) row_ptr[0] = 0;
    }
}

// ---------- fold encoder into layer-0 weights ----------
__global__ __launch_bounds__(256) void fuse_enc(const float* __restrict__ We, const float* __restrict__ be,
                                                const float* __restrict__ Wl, const float* __restrict__ bl,
                                                const float* __restrict__ Wr, const float* __restrict__ br,
                                                float* __restrict__ Wcl, float* __restrict__ bcl,
                                                float* __restrict__ Wcr, float* __restrict__ bcr) {
    __shared__ float sWe[64][64];   // sWe[m][k] = We[k][m]
    __shared__ float sbe[64];
    int t = threadIdx.x;
    for (int i = t; i < 4096; i += 256) sWe[i & 63][i >> 6] = We[i];
    if (t < 64) sbe[t] = be[t];
    __syncthreads();
    int j = t & 127, side = t >> 7;
    const float* W  = side ? Wr : Wl;
    const float* bb = side ? br : bl;
    float acc[64];
#pragma unroll
    for (int k = 0; k < 64; ++k) acc[k] = 0.f;
    float bacc = bb[j];
    for (int m = 0; m < 64; ++m) {
        float wv = W[m * 128 + j];
        bacc += sbe[m] * wv;
#pragma unroll
        for (int k = 0; k < 64; ++k) acc[k] += sWe[m][k] * wv;
    }
    float* Wc = side ? Wcr : Wcl;
#pragma unroll
    for (int k = 0; k < 64; ++k) Wc[k * 128 + j] = acc[k];
    (side ? bcr : bcl)[j] = bacc;
}

// ---------- per-layer transforms, f16 head-interleaved chunks ----------
// node chunk k (16B): [h0 c4k..4k+3 | h1 c4k..4k+3], element idx = (c>>2)*8 + head*4 + (c&3)
template <int BN>
__global__ __launch_bounds__(256) void layer_gemm(const float* __restrict__ hin,
                                                  const float* __restrict__ Wl, const float* __restrict__ bl,
                                                  const float* __restrict__ Wr, const float* __restrict__ br,
                                                  const float* __restrict__ bns, const float* __restrict__ gamma,
                                                  const float* __restrict__ beta,
                                                  unsigned short* __restrict__ xl, unsigned short* __restrict__ xr) {
    __shared__ float ssc[64], ssh[64];
    int t = threadIdx.x;
    if (BN) {
        if (t < 64) {
            float s = 0.f, sq = 0.f;
#pragma unroll
            for (int r = 0; r < 8; ++r) { s += bns[r * 128 + t]; sq += bns[r * 128 + 64 + t]; }
            float mu = s * (1.f / N_NODES);
            float var = sq * (1.f / N_NODES) - mu * mu;
            float sc = gamma[t] * rsqrtf(var + BN_EPS);
            ssc[t] = sc; ssh[t] = beta[t] - mu * sc;
        }
        __syncthreads();
    }
    int tt = t & 127;
    bool isR = t >= 128;
    int c = tt >> 1, head = tt & 1;
    int colW = head * 64 + c;
    int oidx = (c >> 2) * 8 + head * 4 + (c & 3);
    const float* W = isR ? Wr : Wl;
    float wcol[64];
#pragma unroll
    for (int k = 0; k < 64; ++k) wcol[k] = W[k * 128 + colW];
    float bj = (isR ? br : bl)[colW];
    unsigned short* dstp = isR ? xr : xl;
    __shared__ float sh[8][64];
    for (int base = blockIdx.x * 8; base < N_NODES; base += gridDim.x * 8) {
        __syncthreads();
        for (int i = t; i < 512; i += 256) {
            int node = base + (i >> 6);
            float v = (node < N_NODES) ? hin[(size_t)node * 64 + (i & 63)] : 0.f;
            if (BN) v = fmaxf(v * ssc[i & 63] + ssh[i & 63], 0.f);
            sh[i >> 6][i & 63] = v;
        }
        __syncthreads();
        int lim = min(8, N_NODES - base);
        for (int r = 0; r < lim; ++r) {
            float acc = bj;
            const float4* s4 = (const float4*)sh[r];
#pragma unroll
            for (int k4 = 0; k4 < 16; ++k4) {
                float4 v = s4[k4];
                acc += v.x * wcol[4 * k4] + v.y * wcol[4 * k4 + 1] + v.z * wcol[4 * k4 + 2] + v.w * wcol[4 * k4 + 3];
            }
            dstp[(size_t)(base + r) * 128 + oidx] = __builtin_bit_cast(unsigned short, (_Float16)acc);
        }
    }
}

// ---------- fused GATv2 edge phase: packed-f16 math, 3-deep col / 2-deep gather pipeline ----------
__global__ __launch_bounds__(256) void aggregate(const char* __restrict__ xlb,
                                                 const uint4* __restrict__ xr4,
                                                 const int* __restrict__ row_ptr, const int* __restrict__ col,
                                                 const float* __restrict__ att_l, const float* __restrict__ bias_l,
                                                 float* __restrict__ hn, float* __restrict__ bnsum) {
    int lane = threadIdx.x & 63, wid = threadIdx.x >> 6;
    int q = lane >> 4, k = lane & 15;
    int koff = k << 4;
    h2 atA0 = {(_Float16)att_l[4 * k], (_Float16)att_l[4 * k + 1]};
    h2 atA1 = {(_Float16)att_l[4 * k + 2], (_Float16)att_l[4 * k + 3]};
    h2 atB0 = {(_Float16)att_l[64 + 4 * k], (_Float16)att_l[64 + 4 * k + 1]};
    h2 atB1 = {(_Float16)att_l[64 + 4 * k + 2], (_Float16)att_l[64 + 4 * k + 3]};
    float bi0 = bias_l[4 * k], bi1 = bias_l[4 * k + 1], bi2 = bias_l[4 * k + 2], bi3 = bias_l[4 * k + 3];
    const h2 c06 = {(_Float16)0.6f, (_Float16)0.6f};
    const h2 c04 = {(_Float16)0.4f, (_Float16)0.4f};
    float ps[4] = {0, 0, 0, 0}, pq[4] = {0, 0, 0, 0};
    int w = blockIdx.x * 4 + wid, nw = gridDim.x * 4;
    for (int v = w; v < N_NODES; v += nw) {
        uint4 rp = xr4[(size_t)v * 16 + k];
        h2 rA0 = bch2(rp.x), rA1 = bch2(rp.y), rB0 = bch2(rp.z), rB1 = bch2(rp.w);
        int beg = row_ptr[v], end = row_ptr[v + 1];
        float s0 = 0.f, s1 = 0.f;
        h2 aA0 = {0, 0}, aA1 = {0, 0}, aB0 = {0, 0}, aB1 = {0, 0};
        const int* cptr = col + beg + q;      // padded: safe to over-read 32 entries
        int cv0 = cptr[0], cv1 = cptr[4], cv2 = cptr[8], cv3 = cptr[12];
        cptr += 16;
        uint4 lp0 = *(const uint4*)(xlb + (((size_t)(unsigned)cv0) << 8) + koff);
        uint4 lp1 = *(const uint4*)(xlb + (((size_t)(unsigned)cv1) << 8) + koff);
#pragma unroll 2
        for (int i = beg; i < end; i += 4) {
            uint4 lp2 = *(const uint4*)(xlb + (((size_t)(unsigned)cv2) << 8) + koff);
            cv2 = cv3;
            cv3 = *cptr; cptr += 4;
            h2 lA0 = bch2(lp0.x), lA1 = bch2(lp0.y), lB0 = bch2(lp0.z), lB1 = bch2(lp0.w);
            h2 zA0 = lA0 + rA0, zA1 = lA1 + rA1, zB0 = lB0 + rB0, zB1 = lB1 + rB1;
            h2 yA0 = zA0 * c06 + habs2(zA0) * c04;
            h2 yA1 = zA1 * c06 + habs2(zA1) * c04;
            h2 yB0 = zB0 * c06 + habs2(zB0) * c04;
            h2 yB1 = zB1 * c06 + habs2(zB1) * c04;
            float t0 = fdot2f(yA1, atA1, fdot2f(yA0, atA0, 0.f));
            float t1 = fdot2f(yB1, atB1, fdot2f(yB0, atB0, 0.f));
            t0 = rowsum16(t0); t1 = rowsum16(t1);
            bool valid = (i + q) < end;
            float p0 = valid ? __expf(t0) : 0.f;
            float p1 = valid ? __expf(t1) : 0.f;
            s0 += p0; s1 += p1;
            h2 p0h = {(_Float16)p0, (_Float16)p0};
            h2 p1h = {(_Float16)p1, (_Float16)p1};
            aA0 += p0h * lA0; aA1 += p0h * lA1;
            aB0 += p1h * lB0; aB1 += p1h * lB1;
            lp0 = lp1; lp1 = lp2;
        }
#pragma unroll
        for (int o = 16; o <= 32; o <<= 1) {
            s0 += __shfl_xor(s0, o, 64); s1 += __shfl_xor(s1, o, 64);
            aA0 += shflx_h2(aA0, o); aA1 += shflx_h2(aA1, o);
            aB0 += shflx_h2(aB0, o); aB1 += shflx_h2(aB1, o);
        }
        if (q == 0) {
            float i0 = 0.5f / s0, i1 = 0.5f / s1;
            float hv0 = (float)aA0[0] * i0 + (float)aB0[0] * i1 + bi0;
            float hv1 = (float)aA0[1] * i0 + (float)aB0[1] * i1 + bi1;
            float hv2 = (float)aA1[0] * i0 + (float)aB1[0] * i1 + bi2;
            float hv3 = (float)aA1[1] * i0 + (float)aB1[1] * i1 + bi3;
            *(float4*)(hn + (size_t)v * 64 + 4 * k) = make_float4(hv0, hv1, hv2, hv3);
            ps[0] += hv0; pq[0] += hv0 * hv0;
            ps[1] += hv1; pq[1] += hv1 * hv1;
            ps[2] += hv2; pq[2] += hv2 * hv2;
            ps[3] += hv3; pq[3] += hv3 * hv3;
        }
    }
    __shared__ float sb[2][4][64];
    if (q == 0) {
#pragma unroll
        for (int j = 0; j < 4; ++j) { sb[0][wid][4 * k + j] = ps[j]; sb[1][wid][4 * k + j] = pq[j]; }
    }
    __syncthreads();
    float* dstb = bnsum + (size_t)(blockIdx.x & 7) * 128;
    int t = threadIdx.x;
    if (t < 64)
        atomicAdd(&dstb[t], sb[0][0][t] + sb[0][1][t] + sb[0][2][t] + sb[0][3][t]);
    else if (t < 128)
        atomicAdd(&dstb[t], sb[1][0][t - 64] + sb[1][1][t - 64] + sb[1][2][t - 64] + sb[1][3][t - 64]);
}

// ---------- pool: batch sorted -> per-graph blocks via binary search; BN fused ----------
__global__ __launch_bounds__(256) void pool2(const float* __restrict__ hn, const int* __restrict__ batch,
                                             const float* __restrict__ bns, const float* __restrict__ gamma,
                                             const float* __restrict__ beta,
                                             float* __restrict__ gpool, float* __restrict__ gcnt) {
    __shared__ float ssc[64], ssh[64];
    int t = threadIdx.x;
    if (t < 64) {
        float s = 0.f, sq = 0.f;
#pragma unroll
        for (int r = 0; r < 8; ++r) { s += bns[r * 128 + t]; sq += bns[r * 128 + 64 + t]; }
        float mu = s * (1.f / N_NODES);
        float var = sq * (1.f / N_NODES) - mu * mu;
        float sc = gamma[t] * rsqrtf(var + BN_EPS);
        ssc[t] = sc; ssh[t] = beta[t] - mu * sc;
    }
    __syncthreads();
    int g = blockIdx.x >> 2, part = blockIdx.x & 3;
    // lower_bound(batch, key) on sorted batch
    int lo = 0, hi = N_NODES;
    while (lo < hi) { int mid = (lo + hi) >> 1; if (batch[mid] < g) lo = mid + 1; else hi = mid; }
    int lo2 = lo, hi2 = N_NODES;
    while (lo2 < hi2) { int mid = (lo2 + hi2) >> 1; if (batch[mid] < g + 1) lo2 = mid + 1; else hi2 = mid; }
    int len = lo2 - lo;
    if (part == 0 && t == 0) gcnt[g] = (float)len;
    int n0 = lo + (len * part) / 4, n1 = lo + (len * (part + 1)) / 4;
    int c = t & 63, r = t >> 6;
    float sc = ssc[c], sh = ssh[c];
    float acc = 0.f;
    for (int node = n0 + r; node < n1; node += 4)
        acc += fmaxf(hn[(size_t)node * 64 + c] * sc + sh, 0.f);
    __shared__ float sb[4][64];
    sb[r][c] = acc;
    __syncthreads();
    if (r == 0)
        atomicAdd(&gpool[g * 64 + c], sb[0][c] + sb[1][c] + sb[2][c] + sb[3][c]);
}

// ---------- classifier ----------
__global__ void classify(const float* __restrict__ gpool, const float* __restrict__ gcnt,
                         const float* __restrict__ Wc, const float* __restrict__ bc, float* __restrict__ out) {
    int t = threadIdx.x;
    if (t >= 640) return;
    int b = t / 10, o = t % 10;
    float inv = 1.f / fmaxf(gcnt[b], 1.f);
    float acc = 0.f;
    for (int c = 0; c < 64; ++c) acc += gpool[b * 64 + c] * Wc[c * 10 + o];
    out[t] = acc * inv + bc[o];
}

extern "C" void kernel_launch(void* const* d_in, const int* in_sizes, int n_in,
                              void* d_out, int out_size, void* d_ws, size_t ws_size,
                              hipStream_t stream) {
    (void)in_sizes; (void)n_in; (void)out_size; (void)ws_size;
    const float* x     = (const float*)d_in[0];
    const int*   ei    = (const int*)d_in[1];
    const int*   batch = (const int*)d_in[2];
    const float* W_enc = (const float*)d_in[3];
    const float* b_enc = (const float*)d_in[4];
    const float* Wl    = (const float*)d_in[5];
    const float* bl    = (const float*)d_in[6];
    const float* Wr    = (const float*)d_in[7];
    const float* br    = (const float*)d_in[8];
    const float* att   = (const float*)d_in[9];
    const float* bias  = (const float*)d_in[10];
    const float* gamma = (const float*)d_in[11];
    const float* beta  = (const float*)d_in[12];
    const float* Wc    = (const float*)d_in[13];
    const float* bc    = (const float*)d_in[14];
    float* out = (float*)d_out;

    char* ws = (char*)d_ws;
    size_t off = 0;
    auto A = [&](size_t bytes) { size_t r = off; off += (bytes + 255) & ~(size_t)255; return r; };

    int* row_ptr = (int*)(ws + A((N_NODES + 1) * 4));
    // colv followed immediately by the contiguous zero region (one memset)
    size_t colv_off = A((size_t)EP_EDGES * 4 + 426240);
    int* colv = (int*)(ws + colv_off);
    char* zbase = ws + colv_off + (size_t)EP_EDGES * 4;
    // zero-region layout
    int*   cursor = (int*)(zbase + 128);              // 400000 B  (col pad = zbase+0, 128 B)
    int*   gcur   = (int*)(zbase + 400128);           // 1024 B
    float* bns    = (float*)(zbase + 401152);         // 8192 B (2 layers x 8 reps x 128)
    float* gpool  = (float*)(zbase + 409344);         // 16384 B
    float* gcnt   = (float*)(zbase + 425728);         // 256 B
    const size_t ZBYTES = 426240;

    float* h   = (float*)(ws + A((size_t)N_NODES * 64 * 4));
    float* hn  = (float*)(ws + A((size_t)N_NODES * 64 * 4));
    unsigned short* xl = (unsigned short*)(ws + A((size_t)N_NODES * 128 * 2));
    unsigned short* xr = (unsigned short*)(ws + A((size_t)N_NODES * 128 * 2));
    unsigned long long* ebuf = (unsigned long long*)(ws + A((size_t)NREP * NB * SUBREG * 8));
    int* bsum  = (int*)(ws + A(512));
    float* Wcl = (float*)(ws + A(64 * 128 * 4));
    float* Wcr = (float*)(ws + A(64 * 128 * 4));
    float* bcl = (float*)(ws + A(128 * 4));
    float* bcr = (float*)(ws + A(128 * 4));

    const int* srcv = ei;
    const int* dstv = ei + E_EDGES;

    hipMemsetAsync(zbase, 0, ZBYTES, stream);

    bucket_scatter<<<(EP_EDGES + 255) / 256, 256, 0, stream>>>(srcv, dstv, gcur, ebuf);
    bucket_deg<<<NREP * NB, 256, 0, stream>>>(gcur, ebuf, cursor);
    scan_a<<<98, 1024, 0, stream>>>(cursor, row_ptr, bsum);
    scan_c<<<(N_NODES + 255) / 256, 256, 0, stream>>>(cursor, row_ptr, bsum);
    bucket_fine<<<NREP * NB, 256, 0, stream>>>(gcur, ebuf, cursor, colv);

    fuse_enc<<<1, 256, 0, stream>>>(W_enc, b_enc, Wl, bl, Wr, br, Wcl, bcl, Wcr, bcr);

    // layer 0 (encoder folded; reads x directly)
    layer_gemm<0><<<1024, 256, 0, stream>>>(x, Wcl, bcl, Wcr, bcr, bns, gamma, beta, xl, xr);
    aggregate<<<2048, 256, 0, stream>>>((const char*)xl, (const uint4*)xr,
                                        row_ptr, colv, att, bias, hn, bns);
    // layer 1 (BN of layer 0 folded into prologue)
    layer_gemm<1><<<1024, 256, 0, stream>>>(hn, Wl + 64 * 128, bl + 128, Wr + 64 * 128, br + 128,
                                            bns, gamma, beta, xl, xr);
    aggregate<<<2048, 256, 0, stream>>>((const char*)xl, (const uint4*)xr,
                                        row_ptr, colv, att + 128, bias + 64, h, bns + 1024);

    // pool (BN of layer 1 fused) + classifier
    pool2<<<256, 256, 0, stream>>>(h, batch, bns + 1024, gamma + 64, beta + 64, gpool, gcnt);
    classify<<<1, 640, 0, stream>>>(gpool, gcnt, Wc, bc, out);
}

// Round 7
// 469.409 us; speedup vs baseline: 2.1593x; 1.1452x over previous
//
#include <hip/hip_runtime.h>

#define N_NODES 100000
#define E_EDGES 1600000
#define EP_EDGES (E_EDGES + N_NODES)   // 1,700,000 with self loops
#define SLOPE 0.2f
#define BN_EPS 1e-5f
#define NB 8                 // dst buckets (one per XCD)
#define NODES_PER_B 12500
#define NREP 32              // sub-region replicas per bucket
#define SUBREG 8192          // edges per (rep,bucket) sub-region

typedef _Float16 h2 __attribute__((ext_vector_type(2)));

#if defined(__has_builtin)
#if __has_builtin(__builtin_amdgcn_fdot2)
#define HAVE_FDOT2 1
#endif
#endif

__device__ __forceinline__ float fdot2f(h2 a, h2 b, float c) {
#ifdef HAVE_FDOT2
    return __builtin_amdgcn_fdot2(a, b, c, false);
#else
    return c + (float)a[0] * (float)b[0] + (float)a[1] * (float)b[1];
#endif
}
__device__ __forceinline__ h2 bch2(unsigned u) { return __builtin_bit_cast(h2, u); }
__device__ __forceinline__ h2 habs2(h2 z) {
    return __builtin_bit_cast(h2, (unsigned)(__builtin_bit_cast(unsigned, z) & 0x7fff7fffu));
}
__device__ __forceinline__ h2 shflx_h2(h2 a, int o) {
    return __builtin_bit_cast(h2, __shfl_xor(__builtin_bit_cast(int, a), o, 64));
}

// DPP rotate-reduce: sum across each 16-lane row, pure VALU
template <int CTRL>
__device__ __forceinline__ float dpp_add_step(float v) {
    int r = __builtin_amdgcn_update_dpp(0, __float_as_int(v), CTRL, 0xF, 0xF, false);
    return v + __int_as_float(r);
}
__device__ __forceinline__ float rowsum16(float v) {
    v = dpp_add_step<0x128>(v);
    v = dpp_add_step<0x124>(v);
    v = dpp_add_step<0x122>(v);
    v = dpp_add_step<0x121>(v);
    return v;
}

// ---------- bucketed CSR build ----------
__global__ __launch_bounds__(256) void bucket_scatter(const int* __restrict__ src, const int* __restrict__ dst,
                                                      int* __restrict__ gcur, unsigned long long* __restrict__ ebuf) {
    int i = blockIdx.x * 256 + threadIdx.x;
    int rep = blockIdx.x & (NREP - 1);
    bool active = i < EP_EDGES;
    int s = 0, d = 0;
    if (i < E_EDGES) { s = src[i]; d = dst[i]; }
    else if (active) { s = i - E_EDGES; d = s; }
    int b = active ? (int)((unsigned)d / NODES_PER_B) : NB;
    unsigned long long lt = (1ull << (threadIdx.x & 63)) - 1ull;
    int rank = 0;
    unsigned long long mymask = 0;
#pragma unroll
    for (int bb = 0; bb < NB; ++bb) {
        unsigned long long m = __ballot(b == bb);
        if (b == bb) { rank = __popcll(m & lt); mymask = m; }
    }
    int leader = mymask ? (__ffsll((long long)mymask) - 1) : 0;
    int lanebit = threadIdx.x & 63;
    int chunkbase = 0;
    if (active && lanebit == leader)
        chunkbase = atomicAdd(&gcur[rep * NB + b], (int)__popcll(mymask));
    chunkbase = __shfl(chunkbase, leader, 64);
    if (active)
        ebuf[(size_t)(rep * NB + b) * SUBREG + chunkbase + rank] =
            ((unsigned long long)(unsigned)d << 32) | (unsigned)s;
}

// LDS-histogram degree count per (rep,bucket)
__global__ __launch_bounds__(256) void bucket_deg(const int* __restrict__ gcur,
                                                  const unsigned long long* __restrict__ ebuf,
                                                  int* __restrict__ deg) {
    __shared__ int ldeg[NODES_PER_B];
    int b = blockIdx.x & (NB - 1), rep = blockIdx.x >> 3;
    for (int j = threadIdx.x; j < NODES_PER_B; j += 256) ldeg[j] = 0;
    __syncthreads();
    int cnt = gcur[rep * NB + b];
    int base = b * NODES_PER_B;
    const unsigned long long* p = ebuf + (size_t)(rep * NB + b) * SUBREG;
    for (int i = threadIdx.x; i < cnt; i += 256)
        atomicAdd(&ldeg[(int)(p[i] >> 32) - base], 1);
    __syncthreads();
    for (int j = threadIdx.x; j < NODES_PER_B; j += 256) {
        int v = ldeg[j];
        if (v) atomicAdd(&deg[base + j], v);
    }
}

__global__ __launch_bounds__(256) void bucket_fine(const int* __restrict__ gcur,
                                                   const unsigned long long* __restrict__ ebuf,
                                                   int* __restrict__ cursor, int* __restrict__ col) {
    int b = blockIdx.x & (NB - 1), rep = blockIdx.x >> 3;
    int cnt = gcur[rep * NB + b];
    const unsigned long long* p = ebuf + (size_t)(rep * NB + b) * SUBREG;
    for (int i = threadIdx.x; i < cnt; i += 256) {
        unsigned long long e = p[i];
        int d = (int)(e >> 32), s = (int)(e & 0xffffffffu);
        int pos = atomicAdd(&cursor[d], 1);
        col[pos] = s;
    }
}

// ---------- scans for row_ptr ----------
__global__ void scan_a(const int* __restrict__ deg, int* __restrict__ row_ptr, int* __restrict__ bsum) {
    __shared__ int tmp[1024];
    int tid = threadIdx.x;
    int i = blockIdx.x * 1024 + tid;
    int v = (i < N_NODES) ? deg[i] : 0;
    tmp[tid] = v; __syncthreads();
    for (int ofs = 1; ofs < 1024; ofs <<= 1) {
        int t2 = (tid >= ofs) ? tmp[tid - ofs] : 0;
        __syncthreads();
        tmp[tid] += t2;
        __syncthreads();
    }
    if (i < N_NODES) row_ptr[i + 1] = tmp[tid];
    if (tid == 1023) bsum[blockIdx.x] = tmp[1023];
}

// scan_c with inline block-sum prefix
__global__ void scan_c(int* __restrict__ cursor, int* __restrict__ row_ptr, const int* __restrict__ bsum) {
    __shared__ int sp[128];
    int t = threadIdx.x;
    if (t < 128) sp[t] = (t < 98) ? bsum[t] : 0;
    __syncthreads();
    for (int o = 1; o < 128; o <<= 1) {
        int v = (t < 128 && t >= o) ? sp[t - o] : 0;
        __syncthreads();
        if (t < 128) sp[t] += v;
        __syncthreads();
    }
    int i = blockIdx.x * 256 + t;
    if (i < N_NODES) {
        int d = cursor[i];
        int blk = i >> 10;
        int pre = blk ? sp[blk - 1] : 0;
        int incl = row_ptr[i + 1] + pre;
        row_ptr[i + 1] = incl;
        cursor[i] = incl - d;           // exclusive start
        if (i == 0) row_ptr[0] = 0;
    }
}

// ---------- fold encoder into layer-0 weights ----------
__global__ __launch_bounds__(256) void fuse_enc(const float* __restrict__ We, const float* __restrict__ be,
                                                const float* __restrict__ Wl, const float* __restrict__ bl,
                                                const float* __restrict__ Wr, const float* __restrict__ br,
                                                float* __restrict__ Wcl, float* __restrict__ bcl,
                                                float* __restrict__ Wcr, float* __restrict__ bcr) {
    __shared__ float sWe[64][64];   // sWe[m][k] = We[k][m]
    __shared__ float sbe[64];
    int t = threadIdx.x;
    for (int i = t; i < 4096; i += 256) sWe[i & 63][i >> 6] = We[i];
    if (t < 64) sbe[t] = be[t];
    __syncthreads();
    int j = t & 127, side = t >> 7;
    const float* W  = side ? Wr : Wl;
    const float* bb = side ? br : bl;
    float acc[64];
#pragma unroll
    for (int k = 0; k < 64; ++k) acc[k] = 0.f;
    float bacc = bb[j];
    for (int m = 0; m < 64; ++m) {
        float wv = W[m * 128 + j];
        bacc += sbe[m] * wv;
#pragma unroll
        for (int k = 0; k < 64; ++k) acc[k] += sWe[m][k] * wv;
    }
    float* Wc = side ? Wcr : Wcl;
#pragma unroll
    for (int k = 0; k < 64; ++k) Wc[k * 128 + j] = acc[k];
    (side ? bcr : bcl)[j] = bacc;
}

// ---------- per-layer transforms, f16 head-interleaved chunks, dot2 inner loop ----------
// node chunk k (16B): [h0 c4k..4k+3 | h1 c4k..4k+3], element idx = (c>>2)*8 + head*4 + (c&3)
template <int BN>
__global__ __launch_bounds__(256) void layer_gemm(const float* __restrict__ hin,
                                                  const float* __restrict__ Wl, const float* __restrict__ bl,
                                                  const float* __restrict__ Wr, const float* __restrict__ br,
                                                  const float* __restrict__ bns, const float* __restrict__ gamma,
                                                  const float* __restrict__ beta,
                                                  unsigned short* __restrict__ xl, unsigned short* __restrict__ xr) {
    __shared__ float ssc[64], ssh[64];
    int t = threadIdx.x;
    if (BN) {
        if (t < 64) {
            float s = 0.f, sq = 0.f;
#pragma unroll
            for (int r = 0; r < 8; ++r) { s += bns[r * 128 + t]; sq += bns[r * 128 + 64 + t]; }
            float mu = s * (1.f / N_NODES);
            float var = sq * (1.f / N_NODES) - mu * mu;
            float sc = gamma[t] * rsqrtf(var + BN_EPS);
            ssc[t] = sc; ssh[t] = beta[t] - mu * sc;
        }
        __syncthreads();
    }
    int tt = t & 127;
    bool isR = t >= 128;
    int c = tt >> 1, head = tt & 1;
    int colW = head * 64 + c;
    int oidx = (c >> 2) * 8 + head * 4 + (c & 3);
    const float* W = isR ? Wr : Wl;
    // weights packed as 32 h2 (consecutive-k pairs)
    h2 w2[32];
#pragma unroll
    for (int k2 = 0; k2 < 32; ++k2)
        w2[k2] = (h2){(_Float16)W[(2 * k2) * 128 + colW], (_Float16)W[(2 * k2 + 1) * 128 + colW]};
    float bj = (isR ? br : bl)[colW];
    unsigned short* dstp = isR ? xr : xl;
    __shared__ h2 sh[8][36];   // f16-pair rows, +4 pad: conflict-free writes, 16B-aligned rows
    for (int base = blockIdx.x * 8; base < N_NODES; base += gridDim.x * 8) {
        __syncthreads();
        {
            int node = t >> 5, pr = t & 31;
            int gnode = base + node;
            int c0 = pr * 2;
            float2 v = make_float2(0.f, 0.f);
            if (gnode < N_NODES) v = *(const float2*)(hin + (size_t)gnode * 64 + c0);
            if (BN) {
                v.x = fmaxf(v.x * ssc[c0] + ssh[c0], 0.f);
                v.y = fmaxf(v.y * ssc[c0 + 1] + ssh[c0 + 1], 0.f);
            }
            sh[node][pr] = (h2){(_Float16)v.x, (_Float16)v.y};
        }
        __syncthreads();
        int lim = min(8, N_NODES - base);
        for (int r = 0; r < lim; ++r) {
            float acc = bj;
            const uint4* r4 = (const uint4*)(&sh[r][0]);
#pragma unroll
            for (int k4 = 0; k4 < 8; ++k4) {
                uint4 u = r4[k4];
                acc = fdot2f(bch2(u.x), w2[4 * k4 + 0], acc);
                acc = fdot2f(bch2(u.y), w2[4 * k4 + 1], acc);
                acc = fdot2f(bch2(u.z), w2[4 * k4 + 2], acc);
                acc = fdot2f(bch2(u.w), w2[4 * k4 + 3], acc);
            }
            dstp[(size_t)(base + r) * 128 + oidx] = __builtin_bit_cast(unsigned short, (_Float16)acc);
        }
    }
}

// ---------- fused GATv2 edge phase: packed-f16 math, 3-deep col / 2-deep gather pipeline ----------
__global__ __launch_bounds__(256) void aggregate(const char* __restrict__ xlb,
                                                 const uint4* __restrict__ xr4,
                                                 const int* __restrict__ row_ptr, const int* __restrict__ col,
                                                 const float* __restrict__ att_l, const float* __restrict__ bias_l,
                                                 float* __restrict__ hn, float* __restrict__ bnsum) {
    int lane = threadIdx.x & 63, wid = threadIdx.x >> 6;
    int q = lane >> 4, k = lane & 15;
    int koff = k << 4;
    h2 atA0 = {(_Float16)att_l[4 * k], (_Float16)att_l[4 * k + 1]};
    h2 atA1 = {(_Float16)att_l[4 * k + 2], (_Float16)att_l[4 * k + 3]};
    h2 atB0 = {(_Float16)att_l[64 + 4 * k], (_Float16)att_l[64 + 4 * k + 1]};
    h2 atB1 = {(_Float16)att_l[64 + 4 * k + 2], (_Float16)att_l[64 + 4 * k + 3]};
    float bi0 = bias_l[4 * k], bi1 = bias_l[4 * k + 1], bi2 = bias_l[4 * k + 2], bi3 = bias_l[4 * k + 3];
    const h2 c06 = {(_Float16)0.6f, (_Float16)0.6f};
    const h2 c04 = {(_Float16)0.4f, (_Float16)0.4f};
    float ps[4] = {0, 0, 0, 0}, pq[4] = {0, 0, 0, 0};
    int w = blockIdx.x * 4 + wid, nw = gridDim.x * 4;
    for (int v = w; v < N_NODES; v += nw) {
        uint4 rp = xr4[(size_t)v * 16 + k];
        h2 rA0 = bch2(rp.x), rA1 = bch2(rp.y), rB0 = bch2(rp.z), rB1 = bch2(rp.w);
        int beg = row_ptr[v], end = row_ptr[v + 1];
        float s0 = 0.f, s1 = 0.f;
        h2 aA0 = {0, 0}, aA1 = {0, 0}, aB0 = {0, 0}, aB1 = {0, 0};
        const int* cptr = col + beg + q;      // padded: safe to over-read 32 entries
        int cv0 = cptr[0], cv1 = cptr[4], cv2 = cptr[8], cv3 = cptr[12];
        cptr += 16;
        uint4 lp0 = *(const uint4*)(xlb + (((size_t)(unsigned)cv0) << 8) + koff);
        uint4 lp1 = *(const uint4*)(xlb + (((size_t)(unsigned)cv1) << 8) + koff);
#pragma unroll 2
        for (int i = beg; i < end; i += 4) {
            uint4 lp2 = *(const uint4*)(xlb + (((size_t)(unsigned)cv2) << 8) + koff);
            cv2 = cv3;
            cv3 = *cptr; cptr += 4;
            h2 lA0 = bch2(lp0.x), lA1 = bch2(lp0.y), lB0 = bch2(lp0.z), lB1 = bch2(lp0.w);
            h2 zA0 = lA0 + rA0, zA1 = lA1 + rA1, zB0 = lB0 + rB0, zB1 = lB1 + rB1;
            h2 yA0 = zA0 * c06 + habs2(zA0) * c04;
            h2 yA1 = zA1 * c06 + habs2(zA1) * c04;
            h2 yB0 = zB0 * c06 + habs2(zB0) * c04;
            h2 yB1 = zB1 * c06 + habs2(zB1) * c04;
            float t0 = fdot2f(yA1, atA1, fdot2f(yA0, atA0, 0.f));
            float t1 = fdot2f(yB1, atB1, fdot2f(yB0, atB0, 0.f));
            t0 = rowsum16(t0); t1 = rowsum16(t1);
            bool valid = (i + q) < end;
            float p0 = valid ? __expf(t0) : 0.f;
            float p1 = valid ? __expf(t1) : 0.f;
            s0 += p0; s1 += p1;
            h2 p0h = {(_Float16)p0, (_Float16)p0};
            h2 p1h = {(_Float16)p1, (_Float16)p1};
            aA0 += p0h * lA0; aA1 += p0h * lA1;
            aB0 += p1h * lB0; aB1 += p1h * lB1;
            lp0 = lp1; lp1 = lp2;
        }
#pragma unroll
        for (int o = 16; o <= 32; o <<= 1) {
            s0 += __shfl_xor(s0, o, 64); s1 += __shfl_xor(s1, o, 64);
            aA0 += shflx_h2(aA0, o); aA1 += shflx_h2(aA1, o);
            aB0 += shflx_h2(aB0, o); aB1 += shflx_h2(aB1, o);
        }
        if (q == 0) {
            float i0 = 0.5f / s0, i1 = 0.5f / s1;
            float hv0 = (float)aA0[0] * i0 + (float)aB0[0] * i1 + bi0;
            float hv1 = (float)aA0[1] * i0 + (float)aB0[1] * i1 + bi1;
            float hv2 = (float)aA1[0] * i0 + (float)aB1[0] * i1 + bi2;
            float hv3 = (float)aA1[1] * i0 + (float)aB1[1] * i1 + bi3;
            *(float4*)(hn + (size_t)v * 64 + 4 * k) = make_float4(hv0, hv1, hv2, hv3);
            ps[0] += hv0; pq[0] += hv0 * hv0;
            ps[1] += hv1; pq[1] += hv1 * hv1;
            ps[2] += hv2; pq[2] += hv2 * hv2;
            ps[3] += hv3; pq[3] += hv3 * hv3;
        }
    }
    __shared__ float sb[2][4][64];
    if (q == 0) {
#pragma unroll
        for (int j = 0; j < 4; ++j) { sb[0][wid][4 * k + j] = ps[j]; sb[1][wid][4 * k + j] = pq[j]; }
    }
    __syncthreads();
    float* dstb = bnsum + (size_t)(blockIdx.x & 7) * 128;
    int t = threadIdx.x;
    if (t < 64)
        atomicAdd(&dstb[t], sb[0][0][t] + sb[0][1][t] + sb[0][2][t] + sb[0][3][t]);
    else if (t < 128)
        atomicAdd(&dstb[t], sb[1][0][t - 64] + sb[1][1][t - 64] + sb[1][2][t - 64] + sb[1][3][t - 64]);
}

// ---------- pool: batch sorted -> per-graph blocks via binary search; BN fused ----------
__global__ __launch_bounds__(256) void pool2(const float* __restrict__ hn, const int* __restrict__ batch,
                                             const float* __restrict__ bns, const float* __restrict__ gamma,
                                             const float* __restrict__ beta,
                                             float* __restrict__ gpool, float* __restrict__ gcnt) {
    __shared__ float ssc[64], ssh[64];
    int t = threadIdx.x;
    if (t < 64) {
        float s = 0.f, sq = 0.f;
#pragma unroll
        for (int r = 0; r < 8; ++r) { s += bns[r * 128 + t]; sq += bns[r * 128 + 64 + t]; }
        float mu = s * (1.f / N_NODES);
        float var = sq * (1.f / N_NODES) - mu * mu;
        float sc = gamma[t] * rsqrtf(var + BN_EPS);
        ssc[t] = sc; ssh[t] = beta[t] - mu * sc;
    }
    __syncthreads();
    int g = blockIdx.x >> 2, part = blockIdx.x & 3;
    int lo = 0, hi = N_NODES;
    while (lo < hi) { int mid = (lo + hi) >> 1; if (batch[mid] < g) lo = mid + 1; else hi = mid; }
    int lo2 = lo, hi2 = N_NODES;
    while (lo2 < hi2) { int mid = (lo2 + hi2) >> 1; if (batch[mid] < g + 1) lo2 = mid + 1; else hi2 = mid; }
    int len = lo2 - lo;
    if (part == 0 && t == 0) gcnt[g] = (float)len;
    int n0 = lo + (len * part) / 4, n1 = lo + (len * (part + 1)) / 4;
    int c = t & 63, r = t >> 6;
    float sc = ssc[c], sh = ssh[c];
    float acc = 0.f;
    for (int node = n0 + r; node < n1; node += 4)
        acc += fmaxf(hn[(size_t)node * 64 + c] * sc + sh, 0.f);
    __shared__ float sb[4][64];
    sb[r][c] = acc;
    __syncthreads();
    if (r == 0)
        atomicAdd(&gpool[g * 64 + c], sb[0][c] + sb[1][c] + sb[2][c] + sb[3][c]);
}

// ---------- classifier ----------
__global__ void classify(const float* __restrict__ gpool, const float* __restrict__ gcnt,
                         const float* __restrict__ Wc, const float* __restrict__ bc, float* __restrict__ out) {
    int t = threadIdx.x;
    if (t >= 640) return;
    int b = t / 10, o = t % 10;
    float inv = 1.f / fmaxf(gcnt[b], 1.f);
    float acc = 0.f;
    for (int c = 0; c < 64; ++c) acc += gpool[b * 64 + c] * Wc[c * 10 + o];
    out[t] = acc * inv + bc[o];
}

extern "C" void kernel_launch(void* const* d_in, const int* in_sizes, int n_in,
                              void* d_out, int out_size, void* d_ws, size_t ws_size,
                              hipStream_t stream) {
    (void)in_sizes; (void)n_in; (void)out_size; (void)ws_size;
    const float* x     = (const float*)d_in[0];
    const int*   ei    = (const int*)d_in[1];
    const int*   batch = (const int*)d_in[2];
    const float* W_enc = (const float*)d_in[3];
    const float* b_enc = (const float*)d_in[4];
    const float* Wl    = (const float*)d_in[5];
    const float* bl    = (const float*)d_in[6];
    const float* Wr    = (const float*)d_in[7];
    const float* br    = (const float*)d_in[8];
    const float* att   = (const float*)d_in[9];
    const float* bias  = (const float*)d_in[10];
    const float* gamma = (const float*)d_in[11];
    const float* beta  = (const float*)d_in[12];
    const float* Wc    = (const float*)d_in[13];
    const float* bc    = (const float*)d_in[14];
    float* out = (float*)d_out;

    char* ws = (char*)d_ws;
    size_t off = 0;
    auto A = [&](size_t bytes) { size_t r = off; off += (bytes + 255) & ~(size_t)255; return r; };

    int* row_ptr = (int*)(ws + A((N_NODES + 1) * 4));
    // colv followed immediately by the contiguous zero region (one memset)
    size_t colv_off = A((size_t)EP_EDGES * 4 + 426240);
    int* colv = (int*)(ws + colv_off);
    char* zbase = ws + colv_off + (size_t)EP_EDGES * 4;
    int*   cursor = (int*)(zbase + 128);              // 400000 B  (col pad = zbase+0, 128 B)
    int*   gcur   = (int*)(zbase + 400128);           // 1024 B
    float* bns    = (float*)(zbase + 401152);         // 8192 B (2 layers x 8 reps x 128)
    float* gpool  = (float*)(zbase + 409344);         // 16384 B
    float* gcnt   = (float*)(zbase + 425728);         // 256 B
    const size_t ZBYTES = 426240;

    float* h   = (float*)(ws + A((size_t)N_NODES * 64 * 4));
    float* hn  = (float*)(ws + A((size_t)N_NODES * 64 * 4));
    unsigned short* xl = (unsigned short*)(ws + A((size_t)N_NODES * 128 * 2));
    unsigned short* xr = (unsigned short*)(ws + A((size_t)N_NODES * 128 * 2));
    unsigned long long* ebuf = (unsigned long long*)(ws + A((size_t)NREP * NB * SUBREG * 8));
    int* bsum  = (int*)(ws + A(512));
    float* Wcl = (float*)(ws + A(64 * 128 * 4));
    float* Wcr = (float*)(ws + A(64 * 128 * 4));
    float* bcl = (float*)(ws + A(128 * 4));
    float* bcr = (float*)(ws + A(128 * 4));

    const int* srcv = ei;
    const int* dstv = ei + E_EDGES;

    hipMemsetAsync(zbase, 0, ZBYTES, stream);

    bucket_scatter<<<(EP_EDGES + 255) / 256, 256, 0, stream>>>(srcv, dstv, gcur, ebuf);
    bucket_deg<<<NREP * NB, 256, 0, stream>>>(gcur, ebuf, cursor);
    scan_a<<<98, 1024, 0, stream>>>(cursor, row_ptr, bsum);
    scan_c<<<(N_NODES + 255) / 256, 256, 0, stream>>>(cursor, row_ptr, bsum);
    bucket_fine<<<NREP * NB, 256, 0, stream>>>(gcur, ebuf, cursor, colv);

    fuse_enc<<<1, 256, 0, stream>>>(W_enc, b_enc, Wl, bl, Wr, br, Wcl, bcl, Wcr, bcr);

    // layer 0 (encoder folded; reads x directly)
    layer_gemm<0><<<1024, 256, 0, stream>>>(x, Wcl, bcl, Wcr, bcr, bns, gamma, beta, xl, xr);
    aggregate<<<2048, 256, 0, stream>>>((const char*)xl, (const uint4*)xr,
                                        row_ptr, colv, att, bias, hn, bns);
    // layer 1 (BN of layer 0 folded into prologue)
    layer_gemm<1><<<1024, 256, 0, stream>>>(hn, Wl + 64 * 128, bl + 128, Wr + 64 * 128, br + 128,
                                            bns, gamma, beta, xl, xr);
    aggregate<<<2048, 256, 0, stream>>>((const char*)xl, (const uint4*)xr,
                                        row_ptr, colv, att + 128, bias + 64, h, bns + 1024);

    // pool (BN of layer 1 fused) + classifier
    pool2<<<256, 256, 0, stream>>>(h, batch, bns + 1024, gamma + 64, beta + 64, gpool, gcnt);
    classify<<<1, 640, 0, stream>>>(gpool, gcnt, Wc, bc, out);
}

// Round 8
// 456.884 us; speedup vs baseline: 2.2185x; 1.0274x over previous
//
#include <hip/hip_runtime.h>

#define N_NODES 100000
#define E_EDGES 1600000
#define EP_EDGES (E_EDGES + N_NODES)   // 1,700,000 with self loops
#define SLOPE 0.2f
#define BN_EPS 1e-5f
#define NB 8                 // dst buckets (one per XCD)
#define NODES_PER_B 12500
#define NREP 32              // sub-region replicas per bucket
#define SUBREG 8192          // edges per (rep,bucket) sub-region

typedef _Float16 h2 __attribute__((ext_vector_type(2)));

#if defined(__has_builtin)
#if __has_builtin(__builtin_amdgcn_fdot2)
#define HAVE_FDOT2 1
#endif
#endif

__device__ __forceinline__ float fdot2f(h2 a, h2 b, float c) {
#ifdef HAVE_FDOT2
    return __builtin_amdgcn_fdot2(a, b, c, false);
#else
    return c + (float)a[0] * (float)b[0] + (float)a[1] * (float)b[1];
#endif
}
__device__ __forceinline__ h2 bch2(unsigned u) { return __builtin_bit_cast(h2, u); }
__device__ __forceinline__ h2 habs2(h2 z) {
    return __builtin_bit_cast(h2, (unsigned)(__builtin_bit_cast(unsigned, z) & 0x7fff7fffu));
}
__device__ __forceinline__ h2 shflx_h2(h2 a, int o) {
    return __builtin_bit_cast(h2, __shfl_xor(__builtin_bit_cast(int, a), o, 64));
}

// DPP rotate-reduce: sum across each 16-lane row, pure VALU
template <int CTRL>
__device__ __forceinline__ float dpp_add_step(float v) {
    int r = __builtin_amdgcn_update_dpp(0, __float_as_int(v), CTRL, 0xF, 0xF, false);
    return v + __int_as_float(r);
}
__device__ __forceinline__ float rowsum16(float v) {
    v = dpp_add_step<0x128>(v);
    v = dpp_add_step<0x124>(v);
    v = dpp_add_step<0x122>(v);
    v = dpp_add_step<0x121>(v);
    return v;
}

// ---------- bucketed CSR build (u32-packed edges: (dlocal<<17)|src) ----------
__global__ __launch_bounds__(256) void bucket_scatter(const int* __restrict__ src, const int* __restrict__ dst,
                                                      int* __restrict__ gcur, unsigned* __restrict__ ebuf) {
    int i = blockIdx.x * 256 + threadIdx.x;
    int rep = blockIdx.x & (NREP - 1);
    bool active = i < EP_EDGES;
    int s = 0, d = 0;
    if (i < E_EDGES) { s = src[i]; d = dst[i]; }
    else if (active) { s = i - E_EDGES; d = s; }
    int b = active ? (int)((unsigned)d / NODES_PER_B) : NB;
    unsigned long long lt = (1ull << (threadIdx.x & 63)) - 1ull;
    int rank = 0;
    unsigned long long mymask = 0;
#pragma unroll
    for (int bb = 0; bb < NB; ++bb) {
        unsigned long long m = __ballot(b == bb);
        if (b == bb) { rank = __popcll(m & lt); mymask = m; }
    }
    int leader = mymask ? (__ffsll((long long)mymask) - 1) : 0;
    int lanebit = threadIdx.x & 63;
    int chunkbase = 0;
    if (active && lanebit == leader)
        chunkbase = atomicAdd(&gcur[rep * NB + b], (int)__popcll(mymask));
    chunkbase = __shfl(chunkbase, leader, 64);
    if (active) {
        unsigned dl = (unsigned)d - (unsigned)b * NODES_PER_B;
        ebuf[(size_t)(rep * NB + b) * SUBREG + chunkbase + rank] = (dl << 17) | (unsigned)s;
    }
}

// LDS-histogram degree count per (rep,bucket)
__global__ __launch_bounds__(256) void bucket_deg(const int* __restrict__ gcur,
                                                  const unsigned* __restrict__ ebuf,
                                                  int* __restrict__ deg) {
    __shared__ int ldeg[NODES_PER_B];
    int b = blockIdx.x & (NB - 1), rep = blockIdx.x >> 3;
    for (int j = threadIdx.x; j < NODES_PER_B; j += 256) ldeg[j] = 0;
    __syncthreads();
    int cnt = gcur[rep * NB + b];
    int base = b * NODES_PER_B;
    const unsigned* p = ebuf + (size_t)(rep * NB + b) * SUBREG;
    for (int i = threadIdx.x; i < cnt; i += 256)
        atomicAdd(&ldeg[p[i] >> 17], 1);
    __syncthreads();
    for (int j = threadIdx.x; j < NODES_PER_B; j += 256) {
        int v = ldeg[j];
        if (v) atomicAdd(&deg[base + j], v);
    }
}

__global__ __launch_bounds__(256) void bucket_fine(const int* __restrict__ gcur,
                                                   const unsigned* __restrict__ ebuf,
                                                   int* __restrict__ cursor, int* __restrict__ col) {
    int b = blockIdx.x & (NB - 1), rep = blockIdx.x >> 3;
    int cnt = gcur[rep * NB + b];
    int base = b * NODES_PER_B;
    const unsigned* p = ebuf + (size_t)(rep * NB + b) * SUBREG;
    for (int i = threadIdx.x; i < cnt; i += 256) {
        unsigned e = p[i];
        int d = base + (int)(e >> 17), s = (int)(e & 0x1FFFFu);
        int pos = atomicAdd(&cursor[d], 1);
        col[pos] = s;
    }
}

// ---------- scans for row_ptr (wave-scan) ----------
__global__ void scan_a(const int* __restrict__ deg, int* __restrict__ row_ptr, int* __restrict__ bsum) {
    __shared__ int wsum[16];
    int tid = threadIdx.x;
    int lane = tid & 63;
    int i = blockIdx.x * 1024 + tid;
    int x = (i < N_NODES) ? deg[i] : 0;
#pragma unroll
    for (int o = 1; o < 64; o <<= 1) {
        int y = __shfl_up(x, o, 64);
        if (lane >= o) x += y;
    }
    if (lane == 63) wsum[tid >> 6] = x;
    __syncthreads();
    if (tid < 16) {
        int s = wsum[tid];
#pragma unroll
        for (int o = 1; o < 16; o <<= 1) {
            int y = __shfl_up(s, o, 16);
            if (tid >= o) s += y;
        }
        wsum[tid] = s;
    }
    __syncthreads();
    int pre = (tid >= 64) ? wsum[(tid >> 6) - 1] : 0;
    int incl = x + pre;
    if (i < N_NODES) row_ptr[i + 1] = incl;
    if (tid == 1023) bsum[blockIdx.x] = incl;
}

// scan_c with inline block-sum prefix
__global__ void scan_c(int* __restrict__ cursor, int* __restrict__ row_ptr, const int* __restrict__ bsum) {
    __shared__ int sp[128];
    int t = threadIdx.x;
    if (t < 128) sp[t] = (t < 98) ? bsum[t] : 0;
    __syncthreads();
    for (int o = 1; o < 128; o <<= 1) {
        int v = (t < 128 && t >= o) ? sp[t - o] : 0;
        __syncthreads();
        if (t < 128) sp[t] += v;
        __syncthreads();
    }
    int i = blockIdx.x * 256 + t;
    if (i < N_NODES) {
        int d = cursor[i];
        int blk = i >> 10;
        int pre = blk ? sp[blk - 1] : 0;
        int incl = row_ptr[i + 1] + pre;
        row_ptr[i + 1] = incl;
        cursor[i] = incl - d;           // exclusive start
        if (i == 0) row_ptr[0] = 0;
    }
}

// ---------- fold encoder into layer-0 weights ----------
__global__ __launch_bounds__(256) void fuse_enc(const float* __restrict__ We, const float* __restrict__ be,
                                                const float* __restrict__ Wl, const float* __restrict__ bl,
                                                const float* __restrict__ Wr, const float* __restrict__ br,
                                                float* __restrict__ Wcl, float* __restrict__ bcl,
                                                float* __restrict__ Wcr, float* __restrict__ bcr) {
    __shared__ float sWe[64][64];   // sWe[m][k] = We[k][m]
    __shared__ float sbe[64];
    int t = threadIdx.x;
    for (int i = t; i < 4096; i += 256) sWe[i & 63][i >> 6] = We[i];
    if (t < 64) sbe[t] = be[t];
    __syncthreads();
    int j = t & 127, side = t >> 7;
    const float* W  = side ? Wr : Wl;
    const float* bb = side ? br : bl;
    float acc[64];
#pragma unroll
    for (int k = 0; k < 64; ++k) acc[k] = 0.f;
    float bacc = bb[j];
    for (int m = 0; m < 64; ++m) {
        float wv = W[m * 128 + j];
        bacc += sbe[m] * wv;
#pragma unroll
        for (int k = 0; k < 64; ++k) acc[k] += sWe[m][k] * wv;
    }
    float* Wc = side ? Wcr : Wcl;
#pragma unroll
    for (int k = 0; k < 64; ++k) Wc[k * 128 + j] = acc[k];
    (side ? bcr : bcl)[j] = bacc;
}

// ---------- per-layer transforms, f16 chunks; 2 columns/thread, 16-row tiles ----------
// node chunk k (16B): [h0 c4k..4k+3 | h1 c4k..4k+3], element idx = (c>>2)*8 + head*4 + (c&3)
template <int BN>
__global__ __launch_bounds__(256) void layer_gemm(const float* __restrict__ hin,
                                                  const float* __restrict__ Wl, const float* __restrict__ bl,
                                                  const float* __restrict__ Wr, const float* __restrict__ br,
                                                  const float* __restrict__ bns, const float* __restrict__ gamma,
                                                  const float* __restrict__ beta,
                                                  unsigned short* __restrict__ xl, unsigned short* __restrict__ xr) {
    __shared__ float ssc[64], ssh[64];
    int t = threadIdx.x;
    if (BN) {
        if (t < 64) {
            float s = 0.f, sq = 0.f;
#pragma unroll
            for (int r = 0; r < 8; ++r) { s += bns[r * 128 + t]; sq += bns[r * 128 + 64 + t]; }
            float mu = s * (1.f / N_NODES);
            float var = sq * (1.f / N_NODES) - mu * mu;
            float sc = gamma[t] * rsqrtf(var + BN_EPS);
            ssc[t] = sc; ssh[t] = beta[t] - mu * sc;
        }
        __syncthreads();
    }
    int p = t & 127, rh = t >> 7;          // column pair, row half
    int col0 = 2 * p;                       // even: col0,col0+1 same side
    bool isR = col0 >= 128;
    int cw0 = col0 & 127, cw1 = cw0 + 1;
    const float* W = isR ? Wr : Wl;
    h2 w2a[32], w2b[32];
#pragma unroll
    for (int k2 = 0; k2 < 32; ++k2) {
        w2a[k2] = (h2){(_Float16)W[(2 * k2) * 128 + cw0], (_Float16)W[(2 * k2 + 1) * 128 + cw0]};
        w2b[k2] = (h2){(_Float16)W[(2 * k2) * 128 + cw1], (_Float16)W[(2 * k2 + 1) * 128 + cw1]};
    }
    float bja = (isR ? br : bl)[cw0];
    float bjb = (isR ? br : bl)[cw1];
    int head0 = cw0 >> 6, c0 = cw0 & 63;
    int head1 = cw1 >> 6, c1 = cw1 & 63;
    int oidx0 = ((c0 >> 2) << 3) + (head0 << 2) + (c0 & 3);
    int oidx1 = ((c1 >> 2) << 3) + (head1 << 2) + (c1 & 3);
    unsigned short* dstp = isR ? xr : xl;
    __shared__ h2 sh[16][36];   // f16-pair rows, +4 pad
    for (int base = blockIdx.x * 16; base < N_NODES; base += gridDim.x * 16) {
        __syncthreads();
#pragma unroll
        for (int pass = 0; pass < 2; ++pass) {
            int i = t + pass * 256;
            int node = i >> 5, pr = i & 31;
            int gnode = base + node;
            int cc = pr * 2;
            float2 v = make_float2(0.f, 0.f);
            if (gnode < N_NODES) v = *(const float2*)(hin + (size_t)gnode * 64 + cc);
            if (BN) {
                v.x = fmaxf(v.x * ssc[cc] + ssh[cc], 0.f);
                v.y = fmaxf(v.y * ssc[cc + 1] + ssh[cc + 1], 0.f);
            }
            sh[node][pr] = (h2){(_Float16)v.x, (_Float16)v.y};
        }
        __syncthreads();
        int lim = min(16, N_NODES - base);
        int rend = min(rh * 8 + 8, lim);
        for (int r = rh * 8; r < rend; ++r) {
            float acca = bja, accb = bjb;
            const uint4* r4 = (const uint4*)(&sh[r][0]);
#pragma unroll
            for (int k4 = 0; k4 < 8; ++k4) {
                uint4 u = r4[k4];
                acca = fdot2f(bch2(u.x), w2a[4 * k4 + 0], acca);
                accb = fdot2f(bch2(u.x), w2b[4 * k4 + 0], accb);
                acca = fdot2f(bch2(u.y), w2a[4 * k4 + 1], acca);
                accb = fdot2f(bch2(u.y), w2b[4 * k4 + 1], accb);
                acca = fdot2f(bch2(u.z), w2a[4 * k4 + 2], acca);
                accb = fdot2f(bch2(u.z), w2b[4 * k4 + 2], accb);
                acca = fdot2f(bch2(u.w), w2a[4 * k4 + 3], acca);
                accb = fdot2f(bch2(u.w), w2b[4 * k4 + 3], accb);
            }
            size_t rowb = (size_t)(base + r) * 128;
            dstp[rowb + oidx0] = __builtin_bit_cast(unsigned short, (_Float16)acca);
            dstp[rowb + oidx1] = __builtin_bit_cast(unsigned short, (_Float16)accb);
        }
    }
}

// ---------- fused GATv2 edge phase: packed-f16 math, 3-deep col / 2-deep gather pipeline ----------
__global__ __launch_bounds__(256) void aggregate(const char* __restrict__ xlb,
                                                 const uint4* __restrict__ xr4,
                                                 const int* __restrict__ row_ptr, const int* __restrict__ col,
                                                 const float* __restrict__ att_l, const float* __restrict__ bias_l,
                                                 float* __restrict__ hn, float* __restrict__ bnsum) {
    int lane = threadIdx.x & 63, wid = threadIdx.x >> 6;
    int q = lane >> 4, k = lane & 15;
    int koff = k << 4;
    h2 atA0 = {(_Float16)att_l[4 * k], (_Float16)att_l[4 * k + 1]};
    h2 atA1 = {(_Float16)att_l[4 * k + 2], (_Float16)att_l[4 * k + 3]};
    h2 atB0 = {(_Float16)att_l[64 + 4 * k], (_Float16)att_l[64 + 4 * k + 1]};
    h2 atB1 = {(_Float16)att_l[64 + 4 * k + 2], (_Float16)att_l[64 + 4 * k + 3]};
    float bi0 = bias_l[4 * k], bi1 = bias_l[4 * k + 1], bi2 = bias_l[4 * k + 2], bi3 = bias_l[4 * k + 3];
    const h2 c06 = {(_Float16)0.6f, (_Float16)0.6f};
    const h2 c04 = {(_Float16)0.4f, (_Float16)0.4f};
    float ps[4] = {0, 0, 0, 0}, pq[4] = {0, 0, 0, 0};
    int w = blockIdx.x * 4 + wid, nw = gridDim.x * 4;
    for (int v = w; v < N_NODES; v += nw) {
        uint4 rp = xr4[(size_t)v * 16 + k];
        h2 rA0 = bch2(rp.x), rA1 = bch2(rp.y), rB0 = bch2(rp.z), rB1 = bch2(rp.w);
        int beg = row_ptr[v], end = row_ptr[v + 1];
        float s0 = 0.f, s1 = 0.f;
        h2 aA0 = {0, 0}, aA1 = {0, 0}, aB0 = {0, 0}, aB1 = {0, 0};
        const int* cptr = col + beg + q;      // padded: safe to over-read 32 entries
        int cv0 = cptr[0], cv1 = cptr[4], cv2 = cptr[8], cv3 = cptr[12];
        cptr += 16;
        uint4 lp0 = *(const uint4*)(xlb + (((size_t)(unsigned)cv0) << 8) + koff);
        uint4 lp1 = *(const uint4*)(xlb + (((size_t)(unsigned)cv1) << 8) + koff);
#pragma unroll 2
        for (int i = beg; i < end; i += 4) {
            uint4 lp2 = *(const uint4*)(xlb + (((size_t)(unsigned)cv2) << 8) + koff);
            cv2 = cv3;
            cv3 = *cptr; cptr += 4;
            h2 lA0 = bch2(lp0.x), lA1 = bch2(lp0.y), lB0 = bch2(lp0.z), lB1 = bch2(lp0.w);
            h2 zA0 = lA0 + rA0, zA1 = lA1 + rA1, zB0 = lB0 + rB0, zB1 = lB1 + rB1;
            h2 yA0 = zA0 * c06 + habs2(zA0) * c04;
            h2 yA1 = zA1 * c06 + habs2(zA1) * c04;
            h2 yB0 = zB0 * c06 + habs2(zB0) * c04;
            h2 yB1 = zB1 * c06 + habs2(zB1) * c04;
            float t0 = fdot2f(yA1, atA1, fdot2f(yA0, atA0, 0.f));
            float t1 = fdot2f(yB1, atB1, fdot2f(yB0, atB0, 0.f));
            t0 = rowsum16(t0); t1 = rowsum16(t1);
            bool valid = (i + q) < end;
            float p0 = valid ? __expf(t0) : 0.f;
            float p1 = valid ? __expf(t1) : 0.f;
            s0 += p0; s1 += p1;
            h2 p0h = {(_Float16)p0, (_Float16)p0};
            h2 p1h = {(_Float16)p1, (_Float16)p1};
            aA0 += p0h * lA0; aA1 += p0h * lA1;
            aB0 += p1h * lB0; aB1 += p1h * lB1;
            lp0 = lp1; lp1 = lp2;
        }
#pragma unroll
        for (int o = 16; o <= 32; o <<= 1) {
            s0 += __shfl_xor(s0, o, 64); s1 += __shfl_xor(s1, o, 64);
            aA0 += shflx_h2(aA0, o); aA1 += shflx_h2(aA1, o);
            aB0 += shflx_h2(aB0, o); aB1 += shflx_h2(aB1, o);
        }
        if (q == 0) {
            float i0 = 0.5f / s0, i1 = 0.5f / s1;
            float hv0 = (float)aA0[0] * i0 + (float)aB0[0] * i1 + bi0;
            float hv1 = (float)aA0[1] * i0 + (float)aB0[1] * i1 + bi1;
            float hv2 = (float)aA1[0] * i0 + (float)aB1[0] * i1 + bi2;
            float hv3 = (float)aA1[1] * i0 + (float)aB1[1] * i1 + bi3;
            *(float4*)(hn + (size_t)v * 64 + 4 * k) = make_float4(hv0, hv1, hv2, hv3);
            ps[0] += hv0; pq[0] += hv0 * hv0;
            ps[1] += hv1; pq[1] += hv1 * hv1;
            ps[2] += hv2; pq[2] += hv2 * hv2;
            ps[3] += hv3; pq[3] += hv3 * hv3;
        }
    }
    __shared__ float sb[2][4][64];
    if (q == 0) {
#pragma unroll
        for (int j = 0; j < 4; ++j) { sb[0][wid][4 * k + j] = ps[j]; sb[1][wid][4 * k + j] = pq[j]; }
    }
    __syncthreads();
    float* dstb = bnsum + (size_t)(blockIdx.x & 7) * 128;
    int t = threadIdx.x;
    if (t < 64)
        atomicAdd(&dstb[t], sb[0][0][t] + sb[0][1][t] + sb[0][2][t] + sb[0][3][t]);
    else if (t < 128)
        atomicAdd(&dstb[t], sb[1][0][t - 64] + sb[1][1][t - 64] + sb[1][2][t - 64] + sb[1][3][t - 64]);
}

// ---------- pool: batch sorted -> per-graph blocks via binary search; BN fused ----------
__global__ __launch_bounds__(256) void pool2(const float* __restrict__ hn, const int* __restrict__ batch,
                                             const float* __restrict__ bns, const float* __restrict__ gamma,
                                             const float* __restrict__ beta,
                                             float* __restrict__ gpool, float* __restrict__ gcnt) {
    __shared__ float ssc[64], ssh[64];
    int t = threadIdx.x;
    if (t < 64) {
        float s = 0.f, sq = 0.f;
#pragma unroll
        for (int r = 0; r < 8; ++r) { s += bns[r * 128 + t]; sq += bns[r * 128 + 64 + t]; }
        float mu = s * (1.f / N_NODES);
        float var = sq * (1.f / N_NODES) - mu * mu;
        float sc = gamma[t] * rsqrtf(var + BN_EPS);
        ssc[t] = sc; ssh[t] = beta[t] - mu * sc;
    }
    __syncthreads();
    int g = blockIdx.x >> 2, part = blockIdx.x & 3;
    int lo = 0, hi = N_NODES;
    while (lo < hi) { int mid = (lo + hi) >> 1; if (batch[mid] < g) lo = mid + 1; else hi = mid; }
    int lo2 = lo, hi2 = N_NODES;
    while (lo2 < hi2) { int mid = (lo2 + hi2) >> 1; if (batch[mid] < g + 1) lo2 = mid + 1; else hi2 = mid; }
    int len = lo2 - lo;
    if (part == 0 && t == 0) gcnt[g] = (float)len;
    int n0 = lo + (len * part) / 4, n1 = lo + (len * (part + 1)) / 4;
    int c = t & 63, r = t >> 6;
    float sc = ssc[c], sh = ssh[c];
    float acc = 0.f;
    for (int node = n0 + r; node < n1; node += 4)
        acc += fmaxf(hn[(size_t)node * 64 + c] * sc + sh, 0.f);
    __shared__ float sb[4][64];
    sb[r][c] = acc;
    __syncthreads();
    if (r == 0)
        atomicAdd(&gpool[g * 64 + c], sb[0][c] + sb[1][c] + sb[2][c] + sb[3][c]);
}

// ---------- classifier ----------
__global__ void classify(const float* __restrict__ gpool, const float* __restrict__ gcnt,
                         const float* __restrict__ Wc, const float* __restrict__ bc, float* __restrict__ out) {
    int t = threadIdx.x;
    if (t >= 640) return;
    int b = t / 10, o = t % 10;
    float inv = 1.f / fmaxf(gcnt[b], 1.f);
    float acc = 0.f;
    for (int c = 0; c < 64; ++c) acc += gpool[b * 64 + c] * Wc[c * 10 + o];
    out[t] = acc * inv + bc[o];
}

extern "C" void kernel_launch(void* const* d_in, const int* in_sizes, int n_in,
                              void* d_out, int out_size, void* d_ws, size_t ws_size,
                              hipStream_t stream) {
    (void)in_sizes; (void)n_in; (void)out_size; (void)ws_size;
    const float* x     = (const float*)d_in[0];
    const int*   ei    = (const int*)d_in[1];
    const int*   batch = (const int*)d_in[2];
    const float* W_enc = (const float*)d_in[3];
    const float* b_enc = (const float*)d_in[4];
    const float* Wl    = (const float*)d_in[5];
    const float* bl    = (const float*)d_in[6];
    const float* Wr    = (const float*)d_in[7];
    const float* br    = (const float*)d_in[8];
    const float* att   = (const float*)d_in[9];
    const float* bias  = (const float*)d_in[10];
    const float* gamma = (const float*)d_in[11];
    const float* beta  = (const float*)d_in[12];
    const float* Wc    = (const float*)d_in[13];
    const float* bc    = (const float*)d_in[14];
    float* out = (float*)d_out;

    char* ws = (char*)d_ws;
    size_t off = 0;
    auto A = [&](size_t bytes) { size_t r = off; off += (bytes + 255) & ~(size_t)255; return r; };

    int* row_ptr = (int*)(ws + A((N_NODES + 1) * 4));
    // colv followed immediately by the contiguous zero region (one memset)
    size_t colv_off = A((size_t)EP_EDGES * 4 + 426240);
    int* colv = (int*)(ws + colv_off);
    char* zbase = ws + colv_off + (size_t)EP_EDGES * 4;
    int*   cursor = (int*)(zbase + 128);              // 400000 B  (col pad = zbase+0, 128 B)
    int*   gcur   = (int*)(zbase + 400128);           // 1024 B
    float* bns    = (float*)(zbase + 401152);         // 8192 B (2 layers x 8 reps x 128)
    float* gpool  = (float*)(zbase + 409344);         // 16384 B
    float* gcnt   = (float*)(zbase + 425728);         // 256 B
    const size_t ZBYTES = 426240;

    float* h   = (float*)(ws + A((size_t)N_NODES * 64 * 4));
    float* hn  = (float*)(ws + A((size_t)N_NODES * 64 * 4));
    unsigned short* xl = (unsigned short*)(ws + A((size_t)N_NODES * 128 * 2));
    unsigned short* xr = (unsigned short*)(ws + A((size_t)N_NODES * 128 * 2));
    unsigned* ebuf = (unsigned*)(ws + A((size_t)NREP * NB * SUBREG * 4));
    int* bsum  = (int*)(ws + A(512));
    float* Wcl = (float*)(ws + A(64 * 128 * 4));
    float* Wcr = (float*)(ws + A(64 * 128 * 4));
    float* bcl = (float*)(ws + A(128 * 4));
    float* bcr = (float*)(ws + A(128 * 4));

    const int* srcv = ei;
    const int* dstv = ei + E_EDGES;

    hipMemsetAsync(zbase, 0, ZBYTES, stream);

    bucket_scatter<<<(EP_EDGES + 255) / 256, 256, 0, stream>>>(srcv, dstv, gcur, ebuf);
    bucket_deg<<<NREP * NB, 256, 0, stream>>>(gcur, ebuf, cursor);
    scan_a<<<98, 1024, 0, stream>>>(cursor, row_ptr, bsum);
    scan_c<<<(N_NODES + 255) / 256, 256, 0, stream>>>(cursor, row_ptr, bsum);
    bucket_fine<<<NREP * NB, 256, 0, stream>>>(gcur, ebuf, cursor, colv);

    fuse_enc<<<1, 256, 0, stream>>>(W_enc, b_enc, Wl, bl, Wr, br, Wcl, bcl, Wcr, bcr);

    // layer 0 (encoder folded; reads x directly)
    layer_gemm<0><<<1024, 256, 0, stream>>>(x, Wcl, bcl, Wcr, bcr, bns, gamma, beta, xl, xr);
    aggregate<<<4096, 256, 0, stream>>>((const char*)xl, (const uint4*)xr,
                                        row_ptr, colv, att, bias, hn, bns);
    // layer 1 (BN of layer 0 folded into prologue)
    layer_gemm<1><<<1024, 256, 0, stream>>>(hn, Wl + 64 * 128, bl + 128, Wr + 64 * 128, br + 128,
                                            bns, gamma, beta, xl, xr);
    aggregate<<<4096, 256, 0, stream>>>((const char*)xl, (const uint4*)xr,
                                        row_ptr, colv, att + 128, bias + 64, h, bns + 1024);

    // pool (BN of layer 1 fused) + classifier
    pool2<<<256, 256, 0, stream>>>(h, batch, bns + 1024, gamma + 64, beta + 64, gpool, gcnt);
    classify<<<1, 640, 0, stream>>>(gpool, gcnt, Wc, bc, out);
}

// Round 9
// 421.952 us; speedup vs baseline: 2.4022x; 1.0828x over previous
//
#include <hip/hip_runtime.h>

#define N_NODES 100000
#define E_EDGES 1600000
#define EP_EDGES (E_EDGES + N_NODES)   // 1,700,000 with self loops
#define SLOPE 0.2f
#define BN_EPS 1e-5f
#define NB 8                 // dst buckets (one per XCD)
#define NODES_PER_B 12500
#define NREP 32              // sub-region replicas per bucket
#define SUBREG 8192          // edges per (rep,bucket) sub-region
#define SCATTER_BLKS ((EP_EDGES + 255) / 256)

typedef _Float16 h2 __attribute__((ext_vector_type(2)));

#if defined(__has_builtin)
#if __has_builtin(__builtin_amdgcn_fdot2)
#define HAVE_FDOT2 1
#endif
#endif

__device__ __forceinline__ float fdot2f(h2 a, h2 b, float c) {
#ifdef HAVE_FDOT2
    return __builtin_amdgcn_fdot2(a, b, c, false);
#else
    return c + (float)a[0] * (float)b[0] + (float)a[1] * (float)b[1];
#endif
}
__device__ __forceinline__ h2 bch2(unsigned u) { return __builtin_bit_cast(h2, u); }
__device__ __forceinline__ h2 habs2(h2 z) {
    return __builtin_bit_cast(h2, (unsigned)(__builtin_bit_cast(unsigned, z) & 0x7fff7fffu));
}
__device__ __forceinline__ h2 shflx_h2(h2 a, int o) {
    return __builtin_bit_cast(h2, __shfl_xor(__builtin_bit_cast(int, a), o, 64));
}

// DPP rotate-reduce: sum across each 16-lane row, pure VALU
template <int CTRL>
__device__ __forceinline__ float dpp_add_step(float v) {
    int r = __builtin_amdgcn_update_dpp(0, __float_as_int(v), CTRL, 0xF, 0xF, false);
    return v + __int_as_float(r);
}
__device__ __forceinline__ float rowsum16(float v) {
    v = dpp_add_step<0x128>(v);
    v = dpp_add_step<0x124>(v);
    v = dpp_add_step<0x122>(v);
    v = dpp_add_step<0x121>(v);
    return v;
}

// ---------- bucket_scatter body (u32-packed edges: (dlocal<<17)|src) ----------
__device__ __forceinline__ void bucket_scatter_body(int bid, const int* __restrict__ src,
                                                    const int* __restrict__ dst,
                                                    int* __restrict__ gcur, unsigned* __restrict__ ebuf) {
    int i = bid * 256 + threadIdx.x;
    int rep = bid & (NREP - 1);
    bool active = i < EP_EDGES;
    int s = 0, d = 0;
    if (i < E_EDGES) { s = src[i]; d = dst[i]; }
    else if (active) { s = i - E_EDGES; d = s; }
    int b = active ? (int)((unsigned)d / NODES_PER_B) : NB;
    unsigned long long lt = (1ull << (threadIdx.x & 63)) - 1ull;
    int rank = 0;
    unsigned long long mymask = 0;
#pragma unroll
    for (int bb = 0; bb < NB; ++bb) {
        unsigned long long m = __ballot(b == bb);
        if (b == bb) { rank = __popcll(m & lt); mymask = m; }
    }
    int leader = mymask ? (__ffsll((long long)mymask) - 1) : 0;
    int lanebit = threadIdx.x & 63;
    int chunkbase = 0;
    if (active && lanebit == leader)
        chunkbase = atomicAdd(&gcur[rep * NB + b], (int)__popcll(mymask));
    chunkbase = __shfl(chunkbase, leader, 64);
    if (active) {
        unsigned dl = (unsigned)d - (unsigned)b * NODES_PER_B;
        ebuf[(size_t)(rep * NB + b) * SUBREG + chunkbase + rank] = (dl << 17) | (unsigned)s;
    }
}

// ---------- fuse_enc body: fold encoder into layer-0 weights ----------
__device__ __forceinline__ void fuse_enc_body(const float* __restrict__ We, const float* __restrict__ be,
                                              const float* __restrict__ Wl, const float* __restrict__ bl,
                                              const float* __restrict__ Wr, const float* __restrict__ br,
                                              float* __restrict__ Wcl, float* __restrict__ bcl,
                                              float* __restrict__ Wcr, float* __restrict__ bcr,
                                              float (*sWe)[64], float* sbe) {
    int t = threadIdx.x;
    for (int i = t; i < 4096; i += 256) sWe[i & 63][i >> 6] = We[i];
    if (t < 64) sbe[t] = be[t];
    __syncthreads();
    int j = t & 127, side = t >> 7;
    const float* W  = side ? Wr : Wl;
    const float* bb = side ? br : bl;
    float acc[64];
#pragma unroll
    for (int k = 0; k < 64; ++k) acc[k] = 0.f;
    float bacc = bb[j];
    for (int m = 0; m < 64; ++m) {
        float wv = W[m * 128 + j];
        bacc += sbe[m] * wv;
#pragma unroll
        for (int k = 0; k < 64; ++k) acc[k] += sWe[m][k] * wv;
    }
    float* Wc = side ? Wcr : Wcl;
#pragma unroll
    for (int k = 0; k < 64; ++k) Wc[k * 128 + j] = acc[k];
    (side ? bcr : bcl)[j] = bacc;
}

// ---------- combined: block 0 = fuse_enc, blocks 1.. = bucket_scatter ----------
__global__ __launch_bounds__(256) void scatter_fuse(const int* __restrict__ src, const int* __restrict__ dst,
                                                    int* __restrict__ gcur, unsigned* __restrict__ ebuf,
                                                    const float* __restrict__ We, const float* __restrict__ be,
                                                    const float* __restrict__ Wl, const float* __restrict__ bl,
                                                    const float* __restrict__ Wr, const float* __restrict__ br,
                                                    float* __restrict__ Wcl, float* __restrict__ bcl,
                                                    float* __restrict__ Wcr, float* __restrict__ bcr) {
    __shared__ float sWe[64][64];
    __shared__ float sbe[64];
    if (blockIdx.x == 0)
        fuse_enc_body(We, be, Wl, bl, Wr, br, Wcl, bcl, Wcr, bcr, sWe, sbe);
    else
        bucket_scatter_body(blockIdx.x - 1, src, dst, gcur, ebuf);
}

// ---------- LDS-histogram degree count per (rep,bucket) ----------
__global__ __launch_bounds__(256) void bucket_deg(const int* __restrict__ gcur,
                                                  const unsigned* __restrict__ ebuf,
                                                  int* __restrict__ deg) {
    __shared__ int ldeg[NODES_PER_B];
    int b = blockIdx.x & (NB - 1), rep = blockIdx.x >> 3;
    for (int j = threadIdx.x; j < NODES_PER_B; j += 256) ldeg[j] = 0;
    __syncthreads();
    int cnt = gcur[rep * NB + b];
    int base = b * NODES_PER_B;
    const unsigned* p = ebuf + (size_t)(rep * NB + b) * SUBREG;
    for (int i = threadIdx.x; i < cnt; i += 256)
        atomicAdd(&ldeg[p[i] >> 17], 1);
    __syncthreads();
    for (int j = threadIdx.x; j < NODES_PER_B; j += 256) {
        int v = ldeg[j];
        if (v) atomicAdd(&deg[base + j], v);
    }
}

// ---------- bucket_fine body ----------
__device__ __forceinline__ void bucket_fine_body(int bid, const int* __restrict__ gcur,
                                                 const unsigned* __restrict__ ebuf,
                                                 int* __restrict__ cursor, int* __restrict__ col) {
    int b = bid & (NB - 1), rep = bid >> 3;
    int cnt = gcur[rep * NB + b];
    int base = b * NODES_PER_B;
    const unsigned* p = ebuf + (size_t)(rep * NB + b) * SUBREG;
    for (int i = threadIdx.x; i < cnt; i += 256) {
        unsigned e = p[i];
        int d = base + (int)(e >> 17), s = (int)(e & 0x1FFFFu);
        int pos = atomicAdd(&cursor[d], 1);
        col[pos] = s;
    }
}

// ---------- scans for row_ptr (wave-scan) ----------
__global__ void scan_a(const int* __restrict__ deg, int* __restrict__ row_ptr, int* __restrict__ bsum) {
    __shared__ int wsum[16];
    int tid = threadIdx.x;
    int lane = tid & 63;
    int i = blockIdx.x * 1024 + tid;
    int x = (i < N_NODES) ? deg[i] : 0;
#pragma unroll
    for (int o = 1; o < 64; o <<= 1) {
        int y = __shfl_up(x, o, 64);
        if (lane >= o) x += y;
    }
    if (lane == 63) wsum[tid >> 6] = x;
    __syncthreads();
    if (tid < 16) {
        int s = wsum[tid];
#pragma unroll
        for (int o = 1; o < 16; o <<= 1) {
            int y = __shfl_up(s, o, 16);
            if (tid >= o) s += y;
        }
        wsum[tid] = s;
    }
    __syncthreads();
    int pre = (tid >= 64) ? wsum[(tid >> 6) - 1] : 0;
    int incl = x + pre;
    if (i < N_NODES) row_ptr[i + 1] = incl;
    if (tid == 1023) bsum[blockIdx.x] = incl;
}

// scan_c with inline block-sum prefix
__global__ void scan_c(int* __restrict__ cursor, int* __restrict__ row_ptr, const int* __restrict__ bsum) {
    __shared__ int sp[128];
    int t = threadIdx.x;
    if (t < 128) sp[t] = (t < 98) ? bsum[t] : 0;
    __syncthreads();
    for (int o = 1; o < 128; o <<= 1) {
        int v = (t < 128 && t >= o) ? sp[t - o] : 0;
        __syncthreads();
        if (t < 128) sp[t] += v;
        __syncthreads();
    }
    int i = blockIdx.x * 256 + t;
    if (i < N_NODES) {
        int d = cursor[i];
        int blk = i >> 10;
        int pre = blk ? sp[blk - 1] : 0;
        int incl = row_ptr[i + 1] + pre;
        row_ptr[i + 1] = incl;
        cursor[i] = incl - d;           // exclusive start
        if (i == 0) row_ptr[0] = 0;
    }
}

// ---------- per-layer transforms body, f16 chunks; 2 columns/thread, 16-row tiles ----------
// node chunk k (16B): [h0 c4k..4k+3 | h1 c4k..4k+3], element idx = (c>>2)*8 + head*4 + (c&3)
template <int BN>
__device__ __forceinline__ void layer_gemm_body(int bid, int nb,
                                                const float* __restrict__ hin,
                                                const float* __restrict__ Wl, const float* __restrict__ bl,
                                                const float* __restrict__ Wr, const float* __restrict__ br,
                                                const float* __restrict__ bns, const float* __restrict__ gamma,
                                                const float* __restrict__ beta,
                                                unsigned short* __restrict__ xl, unsigned short* __restrict__ xr,
                                                float* ssc, float* ssh, h2 (*sh)[36]) {
    int t = threadIdx.x;
    if (BN) {
        if (t < 64) {
            float s = 0.f, sq = 0.f;
#pragma unroll
            for (int r = 0; r < 8; ++r) { s += bns[r * 128 + t]; sq += bns[r * 128 + 64 + t]; }
            float mu = s * (1.f / N_NODES);
            float var = sq * (1.f / N_NODES) - mu * mu;
            float sc = gamma[t] * rsqrtf(var + BN_EPS);
            ssc[t] = sc; ssh[t] = beta[t] - mu * sc;
        }
        __syncthreads();
    }
    int p = t & 127, rh = t >> 7;          // column pair, row half
    int col0 = 2 * p;                       // even: col0,col0+1 same side
    bool isR = col0 >= 128;
    int cw0 = col0 & 127, cw1 = cw0 + 1;
    const float* W = isR ? Wr : Wl;
    h2 w2a[32], w2b[32];
#pragma unroll
    for (int k2 = 0; k2 < 32; ++k2) {
        w2a[k2] = (h2){(_Float16)W[(2 * k2) * 128 + cw0], (_Float16)W[(2 * k2 + 1) * 128 + cw0]};
        w2b[k2] = (h2){(_Float16)W[(2 * k2) * 128 + cw1], (_Float16)W[(2 * k2 + 1) * 128 + cw1]};
    }
    float bja = (isR ? br : bl)[cw0];
    float bjb = (isR ? br : bl)[cw1];
    int head0 = cw0 >> 6, c0 = cw0 & 63;
    int head1 = cw1 >> 6, c1 = cw1 & 63;
    int oidx0 = ((c0 >> 2) << 3) + (head0 << 2) + (c0 & 3);
    int oidx1 = ((c1 >> 2) << 3) + (head1 << 2) + (c1 & 3);
    unsigned short* dstp = isR ? xr : xl;
    for (int base = bid * 16; base < N_NODES; base += nb * 16) {
        __syncthreads();
#pragma unroll
        for (int pass = 0; pass < 2; ++pass) {
            int i = t + pass * 256;
            int node = i >> 5, pr = i & 31;
            int gnode = base + node;
            int cc = pr * 2;
            float2 v = make_float2(0.f, 0.f);
            if (gnode < N_NODES) v = *(const float2*)(hin + (size_t)gnode * 64 + cc);
            if (BN) {
                v.x = fmaxf(v.x * ssc[cc] + ssh[cc], 0.f);
                v.y = fmaxf(v.y * ssc[cc + 1] + ssh[cc + 1], 0.f);
            }
            sh[node][pr] = (h2){(_Float16)v.x, (_Float16)v.y};
        }
        __syncthreads();
        int lim = min(16, N_NODES - base);
        int rend = min(rh * 8 + 8, lim);
        for (int r = rh * 8; r < rend; ++r) {
            float acca = bja, accb = bjb;
            const uint4* r4 = (const uint4*)(&sh[r][0]);
#pragma unroll
            for (int k4 = 0; k4 < 8; ++k4) {
                uint4 u = r4[k4];
                acca = fdot2f(bch2(u.x), w2a[4 * k4 + 0], acca);
                accb = fdot2f(bch2(u.x), w2b[4 * k4 + 0], accb);
                acca = fdot2f(bch2(u.y), w2a[4 * k4 + 1], acca);
                accb = fdot2f(bch2(u.y), w2b[4 * k4 + 1], accb);
                acca = fdot2f(bch2(u.z), w2a[4 * k4 + 2], acca);
                accb = fdot2f(bch2(u.z), w2b[4 * k4 + 2], accb);
                acca = fdot2f(bch2(u.w), w2a[4 * k4 + 3], acca);
                accb = fdot2f(bch2(u.w), w2b[4 * k4 + 3], accb);
            }
            size_t rowb = (size_t)(base + r) * 128;
            dstp[rowb + oidx0] = __builtin_bit_cast(unsigned short, (_Float16)acca);
            dstp[rowb + oidx1] = __builtin_bit_cast(unsigned short, (_Float16)accb);
        }
    }
}

// ---------- combined: blocks 0..255 = bucket_fine, blocks 256..1279 = layer_gemm<0> ----------
__global__ __launch_bounds__(256) void fine_gemm0(const int* __restrict__ gcur,
                                                  const unsigned* __restrict__ ebuf,
                                                  int* __restrict__ cursor, int* __restrict__ col,
                                                  const float* __restrict__ hin,
                                                  const float* __restrict__ Wl, const float* __restrict__ bl,
                                                  const float* __restrict__ Wr, const float* __restrict__ br,
                                                  unsigned short* __restrict__ xl, unsigned short* __restrict__ xr) {
    __shared__ float ssc[64], ssh[64];
    __shared__ h2 sh[16][36];
    if (blockIdx.x < NREP * NB)
        bucket_fine_body(blockIdx.x, gcur, ebuf, cursor, col);
    else
        layer_gemm_body<0>(blockIdx.x - NREP * NB, 1024, hin, Wl, bl, Wr, br,
                           nullptr, nullptr, nullptr, xl, xr, ssc, ssh, sh);
}

// ---------- standalone layer 1 transform (BN fused) ----------
__global__ __launch_bounds__(256) void layer_gemm1(const float* __restrict__ hin,
                                                   const float* __restrict__ Wl, const float* __restrict__ bl,
                                                   const float* __restrict__ Wr, const float* __restrict__ br,
                                                   const float* __restrict__ bns, const float* __restrict__ gamma,
                                                   const float* __restrict__ beta,
                                                   unsigned short* __restrict__ xl, unsigned short* __restrict__ xr) {
    __shared__ float ssc[64], ssh[64];
    __shared__ h2 sh[16][36];
    layer_gemm_body<1>(blockIdx.x, gridDim.x, hin, Wl, bl, Wr, br, bns, gamma, beta, xl, xr, ssc, ssh, sh);
}

// ---------- fused GATv2 edge phase: packed-f16 math, depth-3 gated prefetch ----------
__global__ __launch_bounds__(256) void aggregate(const char* __restrict__ xlb,
                                                 const uint4* __restrict__ xr4,
                                                 const int* __restrict__ row_ptr, const int* __restrict__ col,
                                                 const float* __restrict__ att_l, const float* __restrict__ bias_l,
                                                 float* __restrict__ hn, float* __restrict__ bnsum) {
    int lane = threadIdx.x & 63, wid = threadIdx.x >> 6;
    int q = lane >> 4, k = lane & 15;
    int koff = k << 4;
    h2 atA0 = {(_Float16)att_l[4 * k], (_Float16)att_l[4 * k + 1]};
    h2 atA1 = {(_Float16)att_l[4 * k + 2], (_Float16)att_l[4 * k + 3]};
    h2 atB0 = {(_Float16)att_l[64 + 4 * k], (_Float16)att_l[64 + 4 * k + 1]};
    h2 atB1 = {(_Float16)att_l[64 + 4 * k + 2], (_Float16)att_l[64 + 4 * k + 3]};
    float bi0 = bias_l[4 * k], bi1 = bias_l[4 * k + 1], bi2 = bias_l[4 * k + 2], bi3 = bias_l[4 * k + 3];
    const h2 c06 = {(_Float16)0.6f, (_Float16)0.6f};
    const h2 c04 = {(_Float16)0.4f, (_Float16)0.4f};
    float ps[4] = {0, 0, 0, 0}, pq[4] = {0, 0, 0, 0};
    int w = blockIdx.x * 4 + wid, nw = gridDim.x * 4;
    for (int v = w; v < N_NODES; v += nw) {
        uint4 rp = xr4[(size_t)v * 16 + k];
        h2 rA0 = bch2(rp.x), rA1 = bch2(rp.y), rB0 = bch2(rp.z), rB1 = bch2(rp.w);
        int beg = row_ptr[v], end = row_ptr[v + 1];
        float s0 = 0.f, s1 = 0.f;
        h2 aA0 = {0, 0}, aA1 = {0, 0}, aB0 = {0, 0}, aB1 = {0, 0};
        const int* cptr = col + beg + q;      // padded: safe to over-read 32 entries
        int cv0 = cptr[0], cv1 = cptr[4], cv2 = cptr[8], cv3 = cptr[12];
        cptr += 16;
        uint4 lp0 = *(const uint4*)(xlb + (((size_t)(unsigned)cv0) << 8) + koff);
        uint4 lp1 = lp0, lp2 = lp0;
        if (beg + 4 < end) lp1 = *(const uint4*)(xlb + (((size_t)(unsigned)cv1) << 8) + koff);
        if (beg + 8 < end) lp2 = *(const uint4*)(xlb + (((size_t)(unsigned)cv2) << 8) + koff);
#pragma unroll 2
        for (int i = beg; i < end; i += 4) {
            uint4 lp3 = lp2;
            if (i + 12 < end) lp3 = *(const uint4*)(xlb + (((size_t)(unsigned)cv3) << 8) + koff);
            cv3 = *cptr; cptr += 4;
            h2 lA0 = bch2(lp0.x), lA1 = bch2(lp0.y), lB0 = bch2(lp0.z), lB1 = bch2(lp0.w);
            h2 zA0 = lA0 + rA0, zA1 = lA1 + rA1, zB0 = lB0 + rB0, zB1 = lB1 + rB1;
            h2 yA0 = zA0 * c06 + habs2(zA0) * c04;
            h2 yA1 = zA1 * c06 + habs2(zA1) * c04;
            h2 yB0 = zB0 * c06 + habs2(zB0) * c04;
            h2 yB1 = zB1 * c06 + habs2(zB1) * c04;
            float t0 = fdot2f(yA1, atA1, fdot2f(yA0, atA0, 0.f));
            float t1 = fdot2f(yB1, atB1, fdot2f(yB0, atB0, 0.f));
            t0 = rowsum16(t0); t1 = rowsum16(t1);
            bool valid = (i + q) < end;
            float p0 = valid ? __expf(t0) : 0.f;
            float p1 = valid ? __expf(t1) : 0.f;
            s0 += p0; s1 += p1;
            h2 p0h = {(_Float16)p0, (_Float16)p0};
            h2 p1h = {(_Float16)p1, (_Float16)p1};
            aA0 += p0h * lA0; aA1 += p0h * lA1;
            aB0 += p1h * lB0; aB1 += p1h * lB1;
            lp0 = lp1; lp1 = lp2; lp2 = lp3;
        }
#pragma unroll
        for (int o = 16; o <= 32; o <<= 1) {
            s0 += __shfl_xor(s0, o, 64); s1 += __shfl_xor(s1, o, 64);
            aA0 += shflx_h2(aA0, o); aA1 += shflx_h2(aA1, o);
            aB0 += shflx_h2(aB0, o); aB1 += shflx_h2(aB1, o);
        }
        if (q == 0) {
            float i0 = 0.5f / s0, i1 = 0.5f / s1;
            float hv0 = (float)aA0[0] * i0 + (float)aB0[0] * i1 + bi0;
            float hv1 = (float)aA0[1] * i0 + (float)aB0[1] * i1 + bi1;
            float hv2 = (float)aA1[0] * i0 + (float)aB1[0] * i1 + bi2;
            float hv3 = (float)aA1[1] * i0 + (float)aB1[1] * i1 + bi3;
            *(float4*)(hn + (size_t)v * 64 + 4 * k) = make_float4(hv0, hv1, hv2, hv3);
            ps[0] += hv0; pq[0] += hv0 * hv0;
            ps[1] += hv1; pq[1] += hv1 * hv1;
            ps[2] += hv2; pq[2] += hv2 * hv2;
            ps[3] += hv3; pq[3] += hv3 * hv3;
        }
    }
    __shared__ float sb[2][4][64];
    if (q == 0) {
#pragma unroll
        for (int j = 0; j < 4; ++j) { sb[0][wid][4 * k + j] = ps[j]; sb[1][wid][4 * k + j] = pq[j]; }
    }
    __syncthreads();
    float* dstb = bnsum + (size_t)(blockIdx.x & 7) * 128;
    int t = threadIdx.x;
    if (t < 64)
        atomicAdd(&dstb[t], sb[0][0][t] + sb[0][1][t] + sb[0][2][t] + sb[0][3][t]);
    else if (t < 128)
        atomicAdd(&dstb[t], sb[1][0][t - 64] + sb[1][1][t - 64] + sb[1][2][t - 64] + sb[1][3][t - 64]);
}

// ---------- pool: batch sorted -> per-graph blocks via binary search; BN fused ----------
__global__ __launch_bounds__(256) void pool2(const float* __restrict__ hn, const int* __restrict__ batch,
                                             const float* __restrict__ bns, const float* __restrict__ gamma,
                                             const float* __restrict__ beta,
                                             float* __restrict__ gpool, float* __restrict__ gcnt) {
    __shared__ float ssc[64], ssh[64];
    int t = threadIdx.x;
    if (t < 64) {
        float s = 0.f, sq = 0.f;
#pragma unroll
        for (int r = 0; r < 8; ++r) { s += bns[r * 128 + t]; sq += bns[r * 128 + 64 + t]; }
        float mu = s * (1.f / N_NODES);
        float var = sq * (1.f / N_NODES) - mu * mu;
        float sc = gamma[t] * rsqrtf(var + BN_EPS);
        ssc[t] = sc; ssh[t] = beta[t] - mu * sc;
    }
    __syncthreads();
    int g = blockIdx.x >> 2, part = blockIdx.x & 3;
    int lo = 0, hi = N_NODES;
    while (lo < hi) { int mid = (lo + hi) >> 1; if (batch[mid] < g) lo = mid + 1; else hi = mid; }
    int lo2 = lo, hi2 = N_NODES;
    while (lo2 < hi2) { int mid = (lo2 + hi2) >> 1; if (batch[mid] < g + 1) lo2 = mid + 1; else hi2 = mid; }
    int len = lo2 - lo;
    if (part == 0 && t == 0) gcnt[g] = (float)len;
    int n0 = lo + (len * part) / 4, n1 = lo + (len * (part + 1)) / 4;
    int c = t & 63, r = t >> 6;
    float sc = ssc[c], sh = ssh[c];
    float acc = 0.f;
    for (int node = n0 + r; node < n1; node += 4)
        acc += fmaxf(hn[(size_t)node * 64 + c] * sc + sh, 0.f);
    __shared__ float sb[4][64];
    sb[r][c] = acc;
    __syncthreads();
    if (r == 0)
        atomicAdd(&gpool[g * 64 + c], sb[0][c] + sb[1][c] + sb[2][c] + sb[3][c]);
}

// ---------- classifier ----------
__global__ void classify(const float* __restrict__ gpool, const float* __restrict__ gcnt,
                         const float* __restrict__ Wc, const float* __restrict__ bc, float* __restrict__ out) {
    int t = threadIdx.x;
    if (t >= 640) return;
    int b = t / 10, o = t % 10;
    float inv = 1.f / fmaxf(gcnt[b], 1.f);
    float acc = 0.f;
    for (int c = 0; c < 64; ++c) acc += gpool[b * 64 + c] * Wc[c * 10 + o];
    out[t] = acc * inv + bc[o];
}

extern "C" void kernel_launch(void* const* d_in, const int* in_sizes, int n_in,
                              void* d_out, int out_size, void* d_ws, size_t ws_size,
                              hipStream_t stream) {
    (void)in_sizes; (void)n_in; (void)out_size; (void)ws_size;
    const float* x     = (const float*)d_in[0];
    const int*   ei    = (const int*)d_in[1];
    const int*   batch = (const int*)d_in[2];
    const float* W_enc = (const float*)d_in[3];
    const float* b_enc = (const float*)d_in[4];
    const float* Wl    = (const float*)d_in[5];
    const float* bl    = (const float*)d_in[6];
    const float* Wr    = (const float*)d_in[7];
    const float* br    = (const float*)d_in[8];
    const float* att   = (const float*)d_in[9];
    const float* bias  = (const float*)d_in[10];
    const float* gamma = (const float*)d_in[11];
    const float* beta  = (const float*)d_in[12];
    const float* Wc    = (const float*)d_in[13];
    const float* bc    = (const float*)d_in[14];
    float* out = (float*)d_out;

    char* ws = (char*)d_ws;
    size_t off = 0;
    auto A = [&](size_t bytes) { size_t r = off; off += (bytes + 255) & ~(size_t)255; return r; };

    int* row_ptr = (int*)(ws + A((N_NODES + 1) * 4));
    // colv followed immediately by the contiguous zero region (one memset)
    size_t colv_off = A((size_t)EP_EDGES * 4 + 426240);
    int* colv = (int*)(ws + colv_off);
    char* zbase = ws + colv_off + (size_t)EP_EDGES * 4;
    int*   cursor = (int*)(zbase + 128);              // 400000 B  (col pad = zbase+0, 128 B)
    int*   gcur   = (int*)(zbase + 400128);           // 1024 B
    float* bns    = (float*)(zbase + 401152);         // 8192 B (2 layers x 8 reps x 128)
    float* gpool  = (float*)(zbase + 409344);         // 16384 B
    float* gcnt   = (float*)(zbase + 425728);         // 256 B
    const size_t ZBYTES = 426240;

    float* h   = (float*)(ws + A((size_t)N_NODES * 64 * 4));
    float* hn  = (float*)(ws + A((size_t)N_NODES * 64 * 4));
    unsigned short* xl = (unsigned short*)(ws + A((size_t)N_NODES * 128 * 2));
    unsigned short* xr = (unsigned short*)(ws + A((size_t)N_NODES * 128 * 2));
    unsigned* ebuf = (unsigned*)(ws + A((size_t)NREP * NB * SUBREG * 4));
    int* bsum  = (int*)(ws + A(512));
    float* Wcl = (float*)(ws + A(64 * 128 * 4));
    float* Wcr = (float*)(ws + A(64 * 128 * 4));
    float* bcl = (float*)(ws + A(128 * 4));
    float* bcr = (float*)(ws + A(128 * 4));

    const int* srcv = ei;
    const int* dstv = ei + E_EDGES;

    hipMemsetAsync(zbase, 0, ZBYTES, stream);

    // bucket_scatter ∥ fuse_enc
    scatter_fuse<<<SCATTER_BLKS + 1, 256, 0, stream>>>(srcv, dstv, gcur, ebuf,
                                                       W_enc, b_enc, Wl, bl, Wr, br,
                                                       Wcl, bcl, Wcr, bcr);
    bucket_deg<<<NREP * NB, 256, 0, stream>>>(gcur, ebuf, cursor);
    scan_a<<<98, 1024, 0, stream>>>(cursor, row_ptr, bsum);
    scan_c<<<(N_NODES + 255) / 256, 256, 0, stream>>>(cursor, row_ptr, bsum);

    // bucket_fine ∥ layer_gemm<0> (encoder folded; reads x directly)
    fine_gemm0<<<NREP * NB + 1024, 256, 0, stream>>>(gcur, ebuf, cursor, colv,
                                                     x, Wcl, bcl, Wcr, bcr, xl, xr);
    aggregate<<<4096, 256, 0, stream>>>((const char*)xl, (const uint4*)xr,
                                        row_ptr, colv, att, bias, hn, bns);
    // layer 1 (BN of layer 0 folded into prologue)
    layer_gemm1<<<1024, 256, 0, stream>>>(hn, Wl + 64 * 128, bl + 128, Wr + 64 * 128, br + 128,
                                          bns, gamma, beta, xl, xr);
    aggregate<<<4096, 256, 0, stream>>>((const char*)xl, (const uint4*)xr,
                                        row_ptr, colv, att + 128, bias + 64, h, bns + 1024);

    // pool (BN of layer 1 fused) + classifier
    pool2<<<256, 256, 0, stream>>>(h, batch, bns + 1024, gamma + 64, beta + 64, gpool, gcnt);
    classify<<<1, 640, 0, stream>>>(gpool, gcnt, Wc, bc, out);
}